// Round 4
// baseline (32862.057 us; speedup 1.0000x reference)
//
#include <hip/hip_runtime.h>
#include <hip/hip_bf16.h>
#include <math.h>

typedef __hip_bfloat16 bf16;

// Problem constants
constexpr int cB = 16, cL = 2048, cWIN = 128, cD = 512, cH = 8, cFF = 2048;
constexpr int cNL = 3, cV = 32000, cM = 32;
constexpr int cHD = cD / cH;     // 64
constexpr int cS = cWIN + 1;     // 129
constexpr float cEPS = 1e-5f;
constexpr float cRECON_W = 0.1f;
constexpr int cNVT = cV / 128;   // 250 vocab tiles

__device__ __forceinline__ float b2f(bf16 x) { return __bfloat162float(x); }

// dtype-agnostic load with ELEMENT offset: f32 flag selects interpretation.
__device__ __forceinline__ float ldx(const void* p, size_t i, int f32) {
    return f32 ? ((const float*)p)[i]
               : __bfloat162float(((const bf16*)p)[i]);
}

// ---------------------------------------------------------------------------
// dtype detection: x0 ~ N(0,1). bf16 data: all halfwords decode |v|<128.
// float32 data: even halfwords are low mantissa bits -> ~47% decode |v|>=128.
__global__ void detect_kernel(const void* __restrict__ x0raw, int* __restrict__ flag)
{
    const unsigned short* h = (const unsigned short*)x0raw;
    int tid = threadIdx.x;
    int cnt = 0;
    for (int j = tid; j < 8192; j += 256) {
        unsigned short u = h[2 * j];
        int e = (u >> 7) & 0xFF;          // bf16 exponent field
        if (e >= 134) cnt++;              // |v| >= 128: impossible for N(0,1) bf16
    }
    __shared__ int red[256];
    red[tid] = cnt; __syncthreads();
    for (int off = 128; off > 0; off >>= 1) {
        if (tid < off) red[tid] += red[tid + off];
        __syncthreads();
    }
    if (tid == 0) *flag = (red[0] > 400) ? 1 : 0;
}

// ---------------------------------------------------------------------------
__global__ __launch_bounds__(512) void pools_kernel(
    const int* __restrict__ tok, const int* __restrict__ mids,
    const int* __restrict__ mlen, const int* __restrict__ wstart,
    const int* __restrict__ wend, const void* __restrict__ emb,
    float* __restrict__ left, float* __restrict__ right,
    float* __restrict__ glob, float* __restrict__ motif,
    const int* __restrict__ dflag)
{
    const int f32 = *dflag;
    int b = blockIdx.x;
    int d = threadIdx.x;
    int ws_ = wstart[b], we_ = wend[b];
    float sl = 0.f, sr = 0.f, sg = 0.f;
    for (int l = 0; l < cL; ++l) {
        int t = tok[b * cL + l];
        float h = ldx(emb, (size_t)t * cD + d, f32);
        sg += h;
        if (l < ws_) sl += h;
        if (l >= we_) sr += h;
    }
    left[b * cD + d]  = sl / fmaxf((float)ws_, 1.f);
    right[b * cD + d] = sr / fmaxf((float)(cL - we_), 1.f);
    glob[b * cD + d]  = sg / (float)cL;
    int ml = mlen[b];
    float sm = 0.f;
    for (int j = 0; j < cM; ++j) {
        if (j < ml) sm += ldx(emb, (size_t)mids[b * cM + j] * cD + d, f32);
    }
    motif[b * cD + d] = sm / fmaxf((float)ml, 1.f);
}

// ---------------------------------------------------------------------------
__global__ __launch_bounds__(512) void cond_temb_kernel(
    const float* __restrict__ motif, const float* __restrict__ left,
    const float* __restrict__ right, const float* __restrict__ glob,
    const void* __restrict__ t_arr,
    const void* __restrict__ cond_W, const void* __restrict__ cond_b,
    const void* __restrict__ tp_W, const void* __restrict__ tp_b,
    float* __restrict__ cond, float* __restrict__ temb,
    const int* __restrict__ dflag)
{
    const int f32 = *dflag;
    __shared__ float feat[4 * cD];
    __shared__ float tf[cD];
    int b = blockIdx.x;
    int d = threadIdx.x;
    feat[d]          = motif[b * cD + d];
    feat[cD + d]     = left[b * cD + d];
    feat[2 * cD + d] = right[b * cD + d];
    feat[3 * cD + d] = glob[b * cD + d];
    float t = ldx(t_arr, b, f32);
    const int half = cD / 2;
    {
        int j = d;
        if (j < half) {
            float fr = expf(-logf(10000.f) * (float)j / (float)(half - 1));
            tf[j] = sinf(t * fr);
        } else {
            float fr = expf(-logf(10000.f) * (float)(j - half) / (float)(half - 1));
            tf[j] = cosf(t * fr);
        }
    }
    __syncthreads();
    float sc = 0.f;
    for (int k = 0; k < 4 * cD; ++k)
        sc += feat[k] * ldx(cond_W, (size_t)d * (4 * cD) + k, f32);
    cond[b * cD + d] = sc + ldx(cond_b, d, f32);
    float st = 0.f;
    for (int k = 0; k < cD; ++k)
        st += tf[k] * ldx(tp_W, (size_t)d * cD + k, f32);
    temb[b * cD + d] = st + ldx(tp_b, d, f32);
}

// ---------------------------------------------------------------------------
__global__ __launch_bounds__(512) void build_x_kernel(
    const int* __restrict__ tok, const int* __restrict__ wstart,
    const int* __restrict__ wend, const void* __restrict__ t_arr,
    const void* __restrict__ x0, const void* __restrict__ emb,
    const float* __restrict__ cond, const float* __restrict__ temb,
    float* __restrict__ x, float* __restrict__ x1, float* __restrict__ xt,
    const int* __restrict__ dflag)
{
    const int f32 = *dflag;
    int row = blockIdx.x;
    int b = row / cS, s = row % cS;
    int d = threadIdx.x;
    if (s == 0) { x[(size_t)row * cD + d] = cond[b * cD + d]; return; }
    int i = s - 1;
    int ws_ = wstart[b], we_ = wend[b];
    int actual = min(max(we_ - ws_, 0), cWIN);
    int idx = min(ws_ + i, cL - 1);
    float x1v = 0.f;
    if (i < actual) x1v = ldx(emb, (size_t)tok[b * cL + idx] * cD + d, f32);
    float t = ldx(t_arr, b, f32);
    float x0v = ldx(x0, ((size_t)b * cWIN + i) * cD + d, f32);
    float xtv = (1.f - t) * x0v + t * x1v;
    size_t ro = ((size_t)b * cWIN + i) * cD + d;
    x1[ro] = x1v;
    xt[ro] = xtv;
    x[(size_t)row * cD + d] = xtv + temb[b * cD + d];
}

// ---------------------------------------------------------------------------
// GEMM: C[M,N] = A[M,K] @ W[N,K]^T + bias (+relu). W/bias flagged dtype with
// ELEMENT offsets wOff/bOff applied in-kernel (host can't know elem size).
constexpr int TSM = 64, TSN = 64, TSK = 16;
__global__ __launch_bounds__(256) void gemm_nt(
    const float* __restrict__ A, const void* __restrict__ Wb, size_t wOff,
    const void* __restrict__ biasb, size_t bOff, float* __restrict__ C,
    int Mdim, int Ndim, int Kdim, int relu, const int* __restrict__ dflag)
{
    const int f32 = *dflag;
    const void* W = f32 ? (const void*)((const float*)Wb + wOff)
                        : (const void*)((const bf16*)Wb + wOff);
    const void* bias = f32 ? (const void*)((const float*)biasb + bOff)
                           : (const void*)((const bf16*)biasb + bOff);
    __shared__ float As[TSM][TSK + 1];
    __shared__ float Bs[TSN][TSK + 1];
    int tid = threadIdx.x;
    int tx = tid % 16;
    int ty = tid / 16;
    int m0 = blockIdx.y * TSM;
    int n0 = blockIdx.x * TSN;
    float acc[4][4] = {};
    for (int k0 = 0; k0 < Kdim; k0 += TSK) {
        for (int i = tid; i < TSM * TSK; i += 256) {
            int r = i / TSK, c = i % TSK;
            int gm = m0 + r;
            As[r][c] = (gm < Mdim) ? A[(size_t)gm * Kdim + k0 + c] : 0.f;
        }
        for (int i = tid; i < TSN * TSK; i += 256) {
            int r = i / TSK, c = i % TSK;
            int gn = n0 + r;
            Bs[r][c] = (gn < Ndim) ? ldx(W, (size_t)gn * Kdim + k0 + c, f32) : 0.f;
        }
        __syncthreads();
        #pragma unroll
        for (int kk = 0; kk < TSK; ++kk) {
            float a[4], bb[4];
            #pragma unroll
            for (int i = 0; i < 4; ++i) a[i] = As[ty * 4 + i][kk];
            #pragma unroll
            for (int j = 0; j < 4; ++j) bb[j] = Bs[tx * 4 + j][kk];
            #pragma unroll
            for (int i = 0; i < 4; ++i)
                #pragma unroll
                for (int j = 0; j < 4; ++j)
                    acc[i][j] += a[i] * bb[j];
        }
        __syncthreads();
    }
    #pragma unroll
    for (int i = 0; i < 4; ++i) {
        int gm = m0 + ty * 4 + i;
        if (gm >= Mdim) continue;
        #pragma unroll
        for (int j = 0; j < 4; ++j) {
            int gn = n0 + tx * 4 + j;
            if (gn >= Ndim) continue;
            float v = acc[i][j] + ldx(bias, gn, f32);
            if (relu) v = fmaxf(v, 0.f);
            C[(size_t)gm * Ndim + gn] = v;
        }
    }
}

// ---------------------------------------------------------------------------
__global__ __launch_bounds__(128) void attn_kernel(
    const float* __restrict__ qkv, float* __restrict__ ctx)
{
    int s = blockIdx.x, h = blockIdx.y, b = blockIdx.z;
    __shared__ float qv[cHD];
    __shared__ float sc[cS];
    __shared__ float red[128];
    int tid = threadIdx.x;
    const float* base = qkv + (size_t)b * cS * (3 * cD);
    if (tid < cHD) qv[tid] = base[(size_t)s * (3 * cD) + h * cHD + tid];
    __syncthreads();
    for (int k = tid; k < cS; k += 128) {
        const float* kv = base + (size_t)k * (3 * cD) + cD + h * cHD;
        float dot = 0.f;
        #pragma unroll
        for (int e = 0; e < cHD; ++e) dot += qv[e] * kv[e];
        sc[k] = dot * 0.125f;
    }
    __syncthreads();
    float m = -1e30f;
    for (int k = tid; k < cS; k += 128) m = fmaxf(m, sc[k]);
    red[tid] = m; __syncthreads();
    for (int off = 64; off > 0; off >>= 1) {
        if (tid < off) red[tid] = fmaxf(red[tid], red[tid + off]);
        __syncthreads();
    }
    m = red[0];
    __syncthreads();
    float sum = 0.f;
    for (int k = tid; k < cS; k += 128) {
        float e = expf(sc[k] - m);
        sc[k] = e;
        sum += e;
    }
    red[tid] = sum; __syncthreads();
    for (int off = 64; off > 0; off >>= 1) {
        if (tid < off) red[tid] += red[tid + off];
        __syncthreads();
    }
    float inv = 1.f / red[0];
    if (tid < cHD) {
        float acc = 0.f;
        for (int k = 0; k < cS; ++k)
            acc += sc[k] * base[(size_t)k * (3 * cD) + 2 * cD + h * cHD + tid];
        ctx[((size_t)(b * cS + s)) * cD + h * cHD + tid] = acc * inv;
    }
}

// ---------------------------------------------------------------------------
// x = LN(x + h); g/beta flagged dtype with element offset.
__global__ __launch_bounds__(256) void resid_ln_kernel(
    float* __restrict__ x, const float* __restrict__ h,
    const void* __restrict__ g, const void* __restrict__ bta, size_t off,
    const int* __restrict__ dflag)
{
    const int f32 = *dflag;
    int row = blockIdx.x;
    int tid = threadIdx.x;
    __shared__ float red[256];
    float v[2];
    float s = 0.f;
    #pragma unroll
    for (int j = 0; j < 2; ++j) {
        int d = tid + j * 256;
        v[j] = x[(size_t)row * cD + d] + h[(size_t)row * cD + d];
        s += v[j];
    }
    red[tid] = s; __syncthreads();
    for (int o = 128; o > 0; o >>= 1) {
        if (tid < o) red[tid] += red[tid + o];
        __syncthreads();
    }
    float mean = red[0] / (float)cD;
    __syncthreads();
    float vs = 0.f;
    #pragma unroll
    for (int j = 0; j < 2; ++j) { float dd = v[j] - mean; vs += dd * dd; }
    red[tid] = vs; __syncthreads();
    for (int o = 128; o > 0; o >>= 1) {
        if (tid < o) red[tid] += red[tid + o];
        __syncthreads();
    }
    float rs = rsqrtf(red[0] / (float)cD + cEPS);
    #pragma unroll
    for (int j = 0; j < 2; ++j) {
        int d = tid + j * 256;
        x[(size_t)row * cD + d] = (v[j] - mean) * rs * ldx(g, off + d, f32)
                                  + ldx(bta, off + d, f32);
    }
}

// ---------------------------------------------------------------------------
__global__ __launch_bounds__(512) void copy_xs_kernel(
    const float* __restrict__ x, float* __restrict__ xs)
{
    int row = blockIdx.x;
    int b = row / cWIN, i = row % cWIN;
    int d = threadIdx.x;
    xs[(size_t)row * cD + d] = x[((size_t)(b * cS + 1 + i)) * cD + d];
}

// ---------------------------------------------------------------------------
__global__ __launch_bounds__(256) void vel_kernel(
    const float* __restrict__ pv, const float* __restrict__ x1,
    const void* __restrict__ x0, const int* __restrict__ wstart,
    const int* __restrict__ wend, float* __restrict__ velpart,
    const int* __restrict__ dflag)
{
    const int f32 = *dflag;
    int row = blockIdx.x;
    int b = row / cWIN, i = row % cWIN;
    int tid = threadIdx.x;
    int actual = min(max(wend[b] - wstart[b], 0), cWIN);
    if (i >= actual) {
        if (tid == 0) velpart[row] = 0.f;
        return;
    }
    __shared__ float red[256];
    float s = 0.f;
    for (int d = tid; d < cD; d += 256) {
        size_t o = (size_t)row * cD + d;
        float tv = x1[o] - ldx(x0, o, f32);
        float diff = pv[o] - tv;
        s += diff * diff;
    }
    red[tid] = s; __syncthreads();
    for (int off = 128; off > 0; off >>= 1) {
        if (tid < off) red[tid] += red[tid + off];
        __syncthreads();
    }
    if (tid == 0) velpart[row] = red[0];
}

// ---------------------------------------------------------------------------
__global__ __launch_bounds__(512) void predx1_kernel(
    const float* __restrict__ xt, const float* __restrict__ pv,
    const void* __restrict__ t_arr, float* __restrict__ outp,
    const int* __restrict__ dflag)
{
    const int f32 = *dflag;
    int row = blockIdx.x;
    int b = row / cWIN;
    int d = threadIdx.x;
    float t = ldx(t_arr, b, f32);
    size_t o = (size_t)row * cD + d;
    outp[o] = xt[o] + (1.f - t) * pv[o];
}

// ---------------------------------------------------------------------------
// labels[row] = token at window position (or -1 if invalid row)
__global__ void labels_kernel(
    const int* __restrict__ tok, const int* __restrict__ wstart,
    const int* __restrict__ wend, int* __restrict__ labels)
{
    int r = blockIdx.x * 256 + threadIdx.x;
    if (r >= cB * cWIN) return;
    int b = r / cWIN, i = r % cWIN;
    int ws_ = wstart[b], we_ = wend[b];
    int actual = min(max(we_ - ws_, 0), cWIN);
    labels[r] = (i < actual) ? tok[b * cL + min(ws_ + i, cL - 1)] : -1;
}

// ---------------------------------------------------------------------------
// decode as tiled GEMM + fused partial log-sum-exp.
// Tile 128x128xK=8, 256 threads, 8x8 micro-tile. Grid (250 vocab, 16 row).
// Writes per-(row, vocab-chunk) partial (max, sumexp) + label logit.
constexpr int DTM = 128, DTN = 128, DTK = 8;
__global__ __launch_bounds__(256) void decode_gemm_kernel(
    const float* __restrict__ H, const void* __restrict__ dW,
    const void* __restrict__ db, const int* __restrict__ labels,
    float* __restrict__ pm, float* __restrict__ ps, float* __restrict__ lab,
    const int* __restrict__ dflag)
{
    const int f32 = *dflag;
    const int nt = blockIdx.x;      // vocab tile 0..249
    const int mt = blockIdx.y;      // row tile 0..15
    const int m0 = mt * DTM, n0 = nt * DTN;
    __shared__ float As[DTK][DTM + 4];
    __shared__ float Bs[DTK][DTN + 4];
    const int tid = threadIdx.x;
    const int tx = tid & 15, ty = tid >> 4;
    float acc[8][8] = {};
    for (int k0 = 0; k0 < cD; k0 += DTK) {
        #pragma unroll
        for (int t = 0; t < 4; ++t) {
            int idx = tid + t * 256;            // 0..1023
            int m = idx >> 3, k = idx & 7;
            As[k][m] = H[(size_t)(m0 + m) * cD + k0 + k];
        }
        #pragma unroll
        for (int t = 0; t < 4; ++t) {
            int idx = tid + t * 256;
            int n = idx >> 3, k = idx & 7;
            Bs[k][n] = ldx(dW, (size_t)(n0 + n) * cD + k0 + k, f32);
        }
        __syncthreads();
        #pragma unroll
        for (int k = 0; k < DTK; ++k) {
            float a[8], b[8];
            #pragma unroll
            for (int i = 0; i < 8; ++i) a[i] = As[k][ty * 8 + i];
            #pragma unroll
            for (int j = 0; j < 8; ++j) b[j] = Bs[k][tx * 8 + j];
            #pragma unroll
            for (int i = 0; i < 8; ++i)
                #pragma unroll
                for (int j = 0; j < 8; ++j)
                    acc[i][j] += a[i] * b[j];
        }
        __syncthreads();
    }
    // bias
    float bias[8];
    #pragma unroll
    for (int j = 0; j < 8; ++j) bias[j] = ldx(db, n0 + tx * 8 + j, f32);
    #pragma unroll
    for (int i = 0; i < 8; ++i)
        #pragma unroll
        for (int j = 0; j < 8; ++j)
            acc[i][j] += bias[j];

    // per-row tile max
    __shared__ float red[DTM][16];
    __shared__ float mrow[DTM];
    #pragma unroll
    for (int i = 0; i < 8; ++i) {
        float mx = acc[i][0];
        #pragma unroll
        for (int j = 1; j < 8; ++j) mx = fmaxf(mx, acc[i][j]);
        red[ty * 8 + i][tx] = mx;
    }
    __syncthreads();
    if (tid < DTM) {
        float mx = red[tid][0];
        #pragma unroll
        for (int t = 1; t < 16; ++t) mx = fmaxf(mx, red[tid][t]);
        mrow[tid] = mx;
    }
    __syncthreads();
    // per-row tile sumexp
    #pragma unroll
    for (int i = 0; i < 8; ++i) {
        float m_ = mrow[ty * 8 + i];
        float s = 0.f;
        #pragma unroll
        for (int j = 0; j < 8; ++j) s += expf(acc[i][j] - m_);
        red[ty * 8 + i][tx] = s;
    }
    __syncthreads();
    if (tid < DTM) {
        float s = red[tid][0];
        #pragma unroll
        for (int t = 1; t < 16; ++t) s += red[tid][t];
        int r = m0 + tid;
        pm[(size_t)r * cNVT + nt] = mrow[tid];
        ps[(size_t)r * cNVT + nt] = s;
    }
    // label logit capture (exactly one block/thread per valid row hits this)
    #pragma unroll
    for (int i = 0; i < 8; ++i) {
        int r = m0 + ty * 8 + i;
        int lb = labels[r];
        int c0 = n0 + tx * 8;
        if (lb >= c0 && lb < c0 + 8) lab[r] = acc[i][lb - c0];
    }
}

// ---------------------------------------------------------------------------
// combine per-chunk (max, sumexp) into logp[label] per row. One wave per row.
__global__ __launch_bounds__(64) void lse_reduce_kernel(
    const float* __restrict__ pm, const float* __restrict__ ps,
    const float* __restrict__ lab, const int* __restrict__ labels,
    float* __restrict__ logppart)
{
    int r = blockIdx.x;
    int tid = threadIdx.x;
    if (labels[r] < 0) {
        if (tid == 0) logppart[r] = 0.f;
        return;
    }
    float m = -1e30f;
    for (int c = tid; c < cNVT; c += 64) m = fmaxf(m, pm[(size_t)r * cNVT + c]);
    for (int off = 32; off > 0; off >>= 1) m = fmaxf(m, __shfl_down(m, off));
    m = __shfl(m, 0);
    float s = 0.f;
    for (int c = tid; c < cNVT; c += 64)
        s += ps[(size_t)r * cNVT + c] * expf(pm[(size_t)r * cNVT + c] - m);
    for (int off = 32; off > 0; off >>= 1) s += __shfl_down(s, off);
    if (tid == 0) logppart[r] = lab[r] - (m + logf(s));
}

// ---------------------------------------------------------------------------
__global__ __launch_bounds__(256) void finalize_kernel(
    const float* __restrict__ velpart, const float* __restrict__ logppart,
    const int* __restrict__ wstart, const int* __restrict__ wend,
    void* __restrict__ out, const int* __restrict__ dflag)
{
    const int f32 = *dflag;
    __shared__ float r1[256], r2[256];
    int tid = threadIdx.x;
    float s1 = 0.f, s2 = 0.f;
    for (int r = tid; r < cB * cWIN; r += 256) {
        s1 += velpart[r];
        s2 += logppart[r];
    }
    r1[tid] = s1; r2[tid] = s2; __syncthreads();
    for (int off = 128; off > 0; off >>= 1) {
        if (tid < off) { r1[tid] += r1[tid + off]; r2[tid] += r2[tid + off]; }
        __syncthreads();
    }
    if (tid == 0) {
        float cnt = 0.f;
        for (int b = 0; b < cB; ++b)
            cnt += (float)min(max(wend[b] - wstart[b], 0), cWIN);
        cnt = fmaxf(cnt, 1.f);
        float vel = r1[0] / (cnt * (float)cD);
        float recon = -r2[0] / cnt;
        float loss = vel + cRECON_W * recon;
        if (f32) ((float*)out)[0] = loss;
        else     ((bf16*)out)[0] = __float2bfloat16(loss);
    }
}

// ===========================================================================
extern "C" void kernel_launch(void* const* d_in, const int* in_sizes, int n_in,
                              void* d_out, int out_size, void* d_ws, size_t ws_size,
                              hipStream_t stream) {
    const int*  token_ids    = (const int*)d_in[0];
    const int*  motif_ids    = (const int*)d_in[1];
    const int*  motif_len    = (const int*)d_in[2];
    const int*  window_start = (const int*)d_in[3];
    const int*  window_end   = (const int*)d_in[4];
    const void* t_arr        = d_in[5];
    const void* x0           = d_in[6];
    const void* embed_table  = d_in[7];
    const void* decode_W     = d_in[8];
    const void* decode_b     = d_in[9];
    const void* adapter_W    = d_in[10];
    const void* adapter_b    = d_in[11];
    const void* time_proj_W  = d_in[12];
    const void* time_proj_b  = d_in[13];
    const void* cond_proj_W  = d_in[14];
    const void* cond_proj_b  = d_in[15];
    const void* qkv_W        = d_in[16];
    const void* qkv_b        = d_in[17];
    const void* attn_out_W   = d_in[18];
    const void* attn_out_b   = d_in[19];
    const void* ff1_W        = d_in[20];
    const void* ff1_b        = d_in[21];
    const void* ff2_W        = d_in[22];
    const void* ff2_b        = d_in[23];
    const void* ln1_g        = d_in[24];
    const void* ln1_b        = d_in[25];
    const void* ln2_g        = d_in[26];
    const void* ln2_b        = d_in[27];
    const void* out_W        = d_in[28];
    const void* out_b        = d_in[29];

    float* w = (float*)d_ws;
    const size_t SZ_X   = (size_t)cB * cS * cD;
    const size_t SZ_BA  = (size_t)cB * cS * cFF;     // 4.23M floats
    const size_t SZ_ROW = (size_t)cB * cWIN * cD;
    float* x     = w;
    float* bufA  = x + SZ_X;
    float* bufB  = bufA + SZ_BA;
    float* bufC  = bufB + SZ_X;
    float* x1b   = bufC + SZ_X;
    float* xtb   = x1b + SZ_ROW;
    float* pvb   = xtb + SZ_ROW;
    float* h2b   = pvb + SZ_ROW;
    float* motif = h2b + SZ_ROW;
    float* left  = motif + (size_t)cB * cD;
    float* right = left + (size_t)cB * cD;
    float* glob  = right + (size_t)cB * cD;
    float* cond  = glob + (size_t)cB * cD;
    float* temb  = cond + (size_t)cB * cD;
    float* velpart = temb + (size_t)cB * cD;
    float* logppart = velpart + (size_t)cB * cWIN;
    int*   dflag = (int*)(logppart + (size_t)cB * cWIN);

    // decode partials live in bufA (free after the FF layers)
    const int Wrows = cB * cWIN;                      // 2048
    float* pm  = bufA;                                // [2048 * 250]
    float* ps  = pm + (size_t)Wrows * cNVT;           // [2048 * 250]
    float* lab = ps + (size_t)Wrows * cNVT;           // [2048]
    int*   labels = (int*)(lab + Wrows);              // [2048]

    const int Mrows = cB * cS;                        // 2064

    detect_kernel<<<1, 256, 0, stream>>>(x0, dflag);
    pools_kernel<<<cB, cD, 0, stream>>>(token_ids, motif_ids, motif_len,
        window_start, window_end, embed_table, left, right, glob, motif, dflag);
    cond_temb_kernel<<<cB, cD, 0, stream>>>(motif, left, right, glob, t_arr,
        cond_proj_W, cond_proj_b, time_proj_W, time_proj_b, cond, temb, dflag);
    build_x_kernel<<<Mrows, cD, 0, stream>>>(token_ids, window_start, window_end,
        t_arr, x0, embed_table, cond, temb, x, x1b, xtb, dflag);

    auto gemm = [&](const float* A, const void* W, size_t wOff,
                    const void* bias, size_t bOff, float* C,
                    int M_, int N_, int K_, int relu) {
        dim3 grid((N_ + TSN - 1) / TSN, (M_ + TSM - 1) / TSM);
        gemm_nt<<<grid, 256, 0, stream>>>(A, W, wOff, bias, bOff, C,
                                          M_, N_, K_, relu, dflag);
    };

    for (int i = 0; i < cNL; ++i) {
        gemm(x, qkv_W, (size_t)i * 3 * cD * cD, qkv_b, (size_t)i * 3 * cD,
             bufA, Mrows, 3 * cD, cD, 0);
        attn_kernel<<<dim3(cS, cH, cB), 128, 0, stream>>>(bufA, bufB);
        gemm(bufB, attn_out_W, (size_t)i * cD * cD, attn_out_b, (size_t)i * cD,
             bufC, Mrows, cD, cD, 0);
        resid_ln_kernel<<<Mrows, 256, 0, stream>>>(x, bufC, ln1_g, ln1_b,
             (size_t)i * cD, dflag);
        gemm(x, ff1_W, (size_t)i * cFF * cD, ff1_b, (size_t)i * cFF,
             bufA, Mrows, cFF, cD, 1);
        gemm(bufA, ff2_W, (size_t)i * cD * cFF, ff2_b, (size_t)i * cD,
             bufC, Mrows, cD, cFF, 0);
        resid_ln_kernel<<<Mrows, 256, 0, stream>>>(x, bufC, ln2_g, ln2_b,
             (size_t)i * cD, dflag);
    }

    copy_xs_kernel<<<Wrows, cD, 0, stream>>>(x, bufC);
    gemm(bufC, out_W, 0, out_b, 0, pvb, Wrows, cD, cD, 0);
    vel_kernel<<<Wrows, 256, 0, stream>>>(pvb, x1b, x0, window_start, window_end,
        velpart, dflag);
    predx1_kernel<<<Wrows, cD, 0, stream>>>(xtb, pvb, t_arr, bufC, dflag);
    gemm(bufC, adapter_W, 0, adapter_b, 0, h2b, Wrows, cD, cD, 0);

    // decode: labels -> tiled GEMM + partial LSE -> per-row reduce
    labels_kernel<<<(Wrows + 255) / 256, 256, 0, stream>>>(
        token_ids, window_start, window_end, labels);
    decode_gemm_kernel<<<dim3(cNVT, Wrows / DTM), 256, 0, stream>>>(
        h2b, decode_W, decode_b, labels, pm, ps, lab, dflag);
    lse_reduce_kernel<<<Wrows, 64, 0, stream>>>(pm, ps, lab, labels, logppart);

    finalize_kernel<<<1, 256, 0, stream>>>(velpart, logppart,
        window_start, window_end, d_out, dflag);
}

// Round 5
// 5109.959 us; speedup vs baseline: 6.4310x; 6.4310x over previous
//
#include <hip/hip_runtime.h>
#include <hip/hip_bf16.h>
#include <math.h>

typedef __hip_bfloat16 bf16;

// Problem constants
constexpr int cB = 16, cL = 2048, cWIN = 128, cD = 512, cH = 8, cFF = 2048;
constexpr int cNL = 3, cV = 32000, cM = 32;
constexpr int cHD = cD / cH;     // 64
constexpr int cS = cWIN + 1;     // 129
constexpr float cEPS = 1e-5f;
constexpr float cRECON_W = 0.1f;
constexpr int cNVT = cV / 128;   // 250 vocab tiles

__device__ __forceinline__ float b2f(bf16 x) { return __bfloat162float(x); }

// dtype-agnostic load with ELEMENT offset: f32 flag selects interpretation.
__device__ __forceinline__ float ldx(const void* p, size_t i, int f32) {
    return f32 ? ((const float*)p)[i]
               : __bfloat162float(((const bf16*)p)[i]);
}

// ---------------------------------------------------------------------------
// dtype detection: x0 ~ N(0,1). bf16 data: all halfwords decode |v|<128.
// float32 data: even halfwords are low mantissa bits -> ~47% decode |v|>=128.
__global__ void detect_kernel(const void* __restrict__ x0raw, int* __restrict__ flag)
{
    const unsigned short* h = (const unsigned short*)x0raw;
    int tid = threadIdx.x;
    int cnt = 0;
    for (int j = tid; j < 8192; j += 256) {
        unsigned short u = h[2 * j];
        int e = (u >> 7) & 0xFF;          // bf16 exponent field
        if (e >= 134) cnt++;              // |v| >= 128: impossible for N(0,1) bf16
    }
    __shared__ int red[256];
    red[tid] = cnt; __syncthreads();
    for (int off = 128; off > 0; off >>= 1) {
        if (tid < off) red[tid] += red[tid + off];
        __syncthreads();
    }
    if (tid == 0) *flag = (red[0] > 400) ? 1 : 0;
}

// ---------------------------------------------------------------------------
__global__ __launch_bounds__(512) void pools_kernel(
    const int* __restrict__ tok, const int* __restrict__ mids,
    const int* __restrict__ mlen, const int* __restrict__ wstart,
    const int* __restrict__ wend, const void* __restrict__ emb,
    float* __restrict__ left, float* __restrict__ right,
    float* __restrict__ glob, float* __restrict__ motif,
    const int* __restrict__ dflag)
{
    const int f32 = *dflag;
    int b = blockIdx.x;
    int d = threadIdx.x;
    int ws_ = wstart[b], we_ = wend[b];
    float sl = 0.f, sr = 0.f, sg = 0.f;
    for (int l = 0; l < cL; ++l) {
        int t = tok[b * cL + l];
        float h = ldx(emb, (size_t)t * cD + d, f32);
        sg += h;
        if (l < ws_) sl += h;
        if (l >= we_) sr += h;
    }
    left[b * cD + d]  = sl / fmaxf((float)ws_, 1.f);
    right[b * cD + d] = sr / fmaxf((float)(cL - we_), 1.f);
    glob[b * cD + d]  = sg / (float)cL;
    int ml = mlen[b];
    float sm = 0.f;
    for (int j = 0; j < cM; ++j) {
        if (j < ml) sm += ldx(emb, (size_t)mids[b * cM + j] * cD + d, f32);
    }
    motif[b * cD + d] = sm / fmaxf((float)ml, 1.f);
}

// ---------------------------------------------------------------------------
__global__ __launch_bounds__(512) void cond_temb_kernel(
    const float* __restrict__ motif, const float* __restrict__ left,
    const float* __restrict__ right, const float* __restrict__ glob,
    const void* __restrict__ t_arr,
    const void* __restrict__ cond_W, const void* __restrict__ cond_b,
    const void* __restrict__ tp_W, const void* __restrict__ tp_b,
    float* __restrict__ cond, float* __restrict__ temb,
    const int* __restrict__ dflag)
{
    const int f32 = *dflag;
    __shared__ float feat[4 * cD];
    __shared__ float tf[cD];
    int b = blockIdx.x;
    int d = threadIdx.x;
    feat[d]          = motif[b * cD + d];
    feat[cD + d]     = left[b * cD + d];
    feat[2 * cD + d] = right[b * cD + d];
    feat[3 * cD + d] = glob[b * cD + d];
    float t = ldx(t_arr, b, f32);
    const int half = cD / 2;
    {
        int j = d;
        if (j < half) {
            float fr = expf(-logf(10000.f) * (float)j / (float)(half - 1));
            tf[j] = sinf(t * fr);
        } else {
            float fr = expf(-logf(10000.f) * (float)(j - half) / (float)(half - 1));
            tf[j] = cosf(t * fr);
        }
    }
    __syncthreads();
    float sc = 0.f;
    for (int k = 0; k < 4 * cD; ++k)
        sc += feat[k] * ldx(cond_W, (size_t)d * (4 * cD) + k, f32);
    cond[b * cD + d] = sc + ldx(cond_b, d, f32);
    float st = 0.f;
    for (int k = 0; k < cD; ++k)
        st += tf[k] * ldx(tp_W, (size_t)d * cD + k, f32);
    temb[b * cD + d] = st + ldx(tp_b, d, f32);
}

// ---------------------------------------------------------------------------
__global__ __launch_bounds__(512) void build_x_kernel(
    const int* __restrict__ tok, const int* __restrict__ wstart,
    const int* __restrict__ wend, const void* __restrict__ t_arr,
    const void* __restrict__ x0, const void* __restrict__ emb,
    const float* __restrict__ cond, const float* __restrict__ temb,
    float* __restrict__ x, float* __restrict__ x1, float* __restrict__ xt,
    const int* __restrict__ dflag)
{
    const int f32 = *dflag;
    int row = blockIdx.x;
    int b = row / cS, s = row % cS;
    int d = threadIdx.x;
    if (s == 0) { x[(size_t)row * cD + d] = cond[b * cD + d]; return; }
    int i = s - 1;
    int ws_ = wstart[b], we_ = wend[b];
    int actual = min(max(we_ - ws_, 0), cWIN);
    int idx = min(ws_ + i, cL - 1);
    float x1v = 0.f;
    if (i < actual) x1v = ldx(emb, (size_t)tok[b * cL + idx] * cD + d, f32);
    float t = ldx(t_arr, b, f32);
    float x0v = ldx(x0, ((size_t)b * cWIN + i) * cD + d, f32);
    float xtv = (1.f - t) * x0v + t * x1v;
    size_t ro = ((size_t)b * cWIN + i) * cD + d;
    x1[ro] = x1v;
    xt[ro] = xtv;
    x[(size_t)row * cD + d] = xtv + temb[b * cD + d];
}

// ---------------------------------------------------------------------------
// GEMM: C[M,N] = A[M,K] @ W[N,K]^T + bias (+relu). W/bias flagged dtype with
// ELEMENT offsets wOff/bOff applied in-kernel (host can't know elem size).
constexpr int TSM = 64, TSN = 64, TSK = 16;
__global__ __launch_bounds__(256) void gemm_nt(
    const float* __restrict__ A, const void* __restrict__ Wb, size_t wOff,
    const void* __restrict__ biasb, size_t bOff, float* __restrict__ C,
    int Mdim, int Ndim, int Kdim, int relu, const int* __restrict__ dflag)
{
    const int f32 = *dflag;
    const void* W = f32 ? (const void*)((const float*)Wb + wOff)
                        : (const void*)((const bf16*)Wb + wOff);
    const void* bias = f32 ? (const void*)((const float*)biasb + bOff)
                           : (const void*)((const bf16*)biasb + bOff);
    __shared__ float As[TSM][TSK + 1];
    __shared__ float Bs[TSN][TSK + 1];
    int tid = threadIdx.x;
    int tx = tid % 16;
    int ty = tid / 16;
    int m0 = blockIdx.y * TSM;
    int n0 = blockIdx.x * TSN;
    float acc[4][4] = {};
    for (int k0 = 0; k0 < Kdim; k0 += TSK) {
        for (int i = tid; i < TSM * TSK; i += 256) {
            int r = i / TSK, c = i % TSK;
            int gm = m0 + r;
            As[r][c] = (gm < Mdim) ? A[(size_t)gm * Kdim + k0 + c] : 0.f;
        }
        for (int i = tid; i < TSN * TSK; i += 256) {
            int r = i / TSK, c = i % TSK;
            int gn = n0 + r;
            Bs[r][c] = (gn < Ndim) ? ldx(W, (size_t)gn * Kdim + k0 + c, f32) : 0.f;
        }
        __syncthreads();
        #pragma unroll
        for (int kk = 0; kk < TSK; ++kk) {
            float a[4], bb[4];
            #pragma unroll
            for (int i = 0; i < 4; ++i) a[i] = As[ty * 4 + i][kk];
            #pragma unroll
            for (int j = 0; j < 4; ++j) bb[j] = Bs[tx * 4 + j][kk];
            #pragma unroll
            for (int i = 0; i < 4; ++i)
                #pragma unroll
                for (int j = 0; j < 4; ++j)
                    acc[i][j] += a[i] * bb[j];
        }
        __syncthreads();
    }
    #pragma unroll
    for (int i = 0; i < 4; ++i) {
        int gm = m0 + ty * 4 + i;
        if (gm >= Mdim) continue;
        #pragma unroll
        for (int j = 0; j < 4; ++j) {
            int gn = n0 + tx * 4 + j;
            if (gn >= Ndim) continue;
            float v = acc[i][j] + ldx(bias, gn, f32);
            if (relu) v = fmaxf(v, 0.f);
            C[(size_t)gm * Ndim + gn] = v;
        }
    }
}

// ---------------------------------------------------------------------------
__global__ __launch_bounds__(128) void attn_kernel(
    const float* __restrict__ qkv, float* __restrict__ ctx)
{
    int s = blockIdx.x, h = blockIdx.y, b = blockIdx.z;
    __shared__ float qv[cHD];
    __shared__ float sc[cS];
    __shared__ float red[128];
    int tid = threadIdx.x;
    const float* base = qkv + (size_t)b * cS * (3 * cD);
    if (tid < cHD) qv[tid] = base[(size_t)s * (3 * cD) + h * cHD + tid];
    __syncthreads();
    for (int k = tid; k < cS; k += 128) {
        const float* kv = base + (size_t)k * (3 * cD) + cD + h * cHD;
        float dot = 0.f;
        #pragma unroll
        for (int e = 0; e < cHD; ++e) dot += qv[e] * kv[e];
        sc[k] = dot * 0.125f;
    }
    __syncthreads();
    float m = -1e30f;
    for (int k = tid; k < cS; k += 128) m = fmaxf(m, sc[k]);
    red[tid] = m; __syncthreads();
    for (int off = 64; off > 0; off >>= 1) {
        if (tid < off) red[tid] = fmaxf(red[tid], red[tid + off]);
        __syncthreads();
    }
    m = red[0];
    __syncthreads();
    float sum = 0.f;
    for (int k = tid; k < cS; k += 128) {
        float e = expf(sc[k] - m);
        sc[k] = e;
        sum += e;
    }
    red[tid] = sum; __syncthreads();
    for (int off = 64; off > 0; off >>= 1) {
        if (tid < off) red[tid] += red[tid + off];
        __syncthreads();
    }
    float inv = 1.f / red[0];
    if (tid < cHD) {
        float acc = 0.f;
        for (int k = 0; k < cS; ++k)
            acc += sc[k] * base[(size_t)k * (3 * cD) + 2 * cD + h * cHD + tid];
        ctx[((size_t)(b * cS + s)) * cD + h * cHD + tid] = acc * inv;
    }
}

// ---------------------------------------------------------------------------
// x = LN(x + h); g/beta flagged dtype with element offset.
__global__ __launch_bounds__(256) void resid_ln_kernel(
    float* __restrict__ x, const float* __restrict__ h,
    const void* __restrict__ g, const void* __restrict__ bta, size_t off,
    const int* __restrict__ dflag)
{
    const int f32 = *dflag;
    int row = blockIdx.x;
    int tid = threadIdx.x;
    __shared__ float red[256];
    float v[2];
    float s = 0.f;
    #pragma unroll
    for (int j = 0; j < 2; ++j) {
        int d = tid + j * 256;
        v[j] = x[(size_t)row * cD + d] + h[(size_t)row * cD + d];
        s += v[j];
    }
    red[tid] = s; __syncthreads();
    for (int o = 128; o > 0; o >>= 1) {
        if (tid < o) red[tid] += red[tid + o];
        __syncthreads();
    }
    float mean = red[0] / (float)cD;
    __syncthreads();
    float vs = 0.f;
    #pragma unroll
    for (int j = 0; j < 2; ++j) { float dd = v[j] - mean; vs += dd * dd; }
    red[tid] = vs; __syncthreads();
    for (int o = 128; o > 0; o >>= 1) {
        if (tid < o) red[tid] += red[tid + o];
        __syncthreads();
    }
    float rs = rsqrtf(red[0] / (float)cD + cEPS);
    #pragma unroll
    for (int j = 0; j < 2; ++j) {
        int d = tid + j * 256;
        x[(size_t)row * cD + d] = (v[j] - mean) * rs * ldx(g, off + d, f32)
                                  + ldx(bta, off + d, f32);
    }
}

// ---------------------------------------------------------------------------
__global__ __launch_bounds__(512) void copy_xs_kernel(
    const float* __restrict__ x, float* __restrict__ xs)
{
    int row = blockIdx.x;
    int b = row / cWIN, i = row % cWIN;
    int d = threadIdx.x;
    xs[(size_t)row * cD + d] = x[((size_t)(b * cS + 1 + i)) * cD + d];
}

// ---------------------------------------------------------------------------
__global__ __launch_bounds__(256) void vel_kernel(
    const float* __restrict__ pv, const float* __restrict__ x1,
    const void* __restrict__ x0, const int* __restrict__ wstart,
    const int* __restrict__ wend, float* __restrict__ velpart,
    const int* __restrict__ dflag)
{
    const int f32 = *dflag;
    int row = blockIdx.x;
    int b = row / cWIN, i = row % cWIN;
    int tid = threadIdx.x;
    int actual = min(max(wend[b] - wstart[b], 0), cWIN);
    if (i >= actual) {
        if (tid == 0) velpart[row] = 0.f;
        return;
    }
    __shared__ float red[256];
    float s = 0.f;
    for (int d = tid; d < cD; d += 256) {
        size_t o = (size_t)row * cD + d;
        float tv = x1[o] - ldx(x0, o, f32);
        float diff = pv[o] - tv;
        s += diff * diff;
    }
    red[tid] = s; __syncthreads();
    for (int off = 128; off > 0; off >>= 1) {
        if (tid < off) red[tid] += red[tid + off];
        __syncthreads();
    }
    if (tid == 0) velpart[row] = red[0];
}

// ---------------------------------------------------------------------------
__global__ __launch_bounds__(512) void predx1_kernel(
    const float* __restrict__ xt, const float* __restrict__ pv,
    const void* __restrict__ t_arr, float* __restrict__ outp,
    const int* __restrict__ dflag)
{
    const int f32 = *dflag;
    int row = blockIdx.x;
    int b = row / cWIN;
    int d = threadIdx.x;
    float t = ldx(t_arr, b, f32);
    size_t o = (size_t)row * cD + d;
    outp[o] = xt[o] + (1.f - t) * pv[o];
}

// ---------------------------------------------------------------------------
// labels[row] = token at window position (or -1 if invalid row)
__global__ void labels_kernel(
    const int* __restrict__ tok, const int* __restrict__ wstart,
    const int* __restrict__ wend, int* __restrict__ labels)
{
    int r = blockIdx.x * 256 + threadIdx.x;
    if (r >= cB * cWIN) return;
    int b = r / cWIN, i = r % cWIN;
    int ws_ = wstart[b], we_ = wend[b];
    int actual = min(max(we_ - ws_, 0), cWIN);
    labels[r] = (i < actual) ? tok[b * cL + min(ws_ + i, cL - 1)] : -1;
}

// ---------------------------------------------------------------------------
// decode as tiled GEMM + fused partial log-sum-exp.
// Tile 128x128xK=8, 256 threads, 8x8 micro-tile in SPLIT form:
//   rows  {ty*4+0..3} U {64+ty*4+0..3}, cols {tx*4+0..3} U {64+tx*4+0..3}
// (split micro-tile -> LDS reads at stride 4 = 2-way bank alias = free).
// NO dynamic indexing into acc[][] (scratch-spill trap, R4 post-mortem).
constexpr int DTM = 128, DTN = 128, DTK = 8;
__device__ __forceinline__ int dg_row(int ty, int i) {
    return ty * 4 + (i & 3) + ((i >> 2) << 6);
}
__global__ __launch_bounds__(256) void decode_gemm_kernel(
    const float* __restrict__ H, const void* __restrict__ dW,
    const void* __restrict__ db, const int* __restrict__ labels,
    float* __restrict__ pm, float* __restrict__ ps, float* __restrict__ lab,
    const int* __restrict__ dflag)
{
    const int f32 = *dflag;
    const int nt = blockIdx.x;      // vocab tile 0..249
    const int mt = blockIdx.y;      // row tile 0..15
    const int m0 = mt * DTM, n0 = nt * DTN;
    __shared__ float As[DTK][DTM + 4];
    __shared__ float Bs[DTK][DTN + 4];
    const int tid = threadIdx.x;
    const int tx = tid & 15, ty = tid >> 4;
    float acc[8][8] = {};
    for (int k0 = 0; k0 < cD; k0 += DTK) {
        #pragma unroll
        for (int t = 0; t < 4; ++t) {
            int idx = tid + t * 256;            // 0..1023
            int m = idx >> 3, k = idx & 7;
            As[k][m] = H[(size_t)(m0 + m) * cD + k0 + k];
        }
        #pragma unroll
        for (int t = 0; t < 4; ++t) {
            int idx = tid + t * 256;
            int n = idx >> 3, k = idx & 7;
            Bs[k][n] = ldx(dW, (size_t)(n0 + n) * cD + k0 + k, f32);
        }
        __syncthreads();
        #pragma unroll
        for (int k = 0; k < DTK; ++k) {
            float a[8], b[8];
            #pragma unroll
            for (int i = 0; i < 4; ++i) {
                a[i]     = As[k][ty * 4 + i];
                a[i + 4] = As[k][64 + ty * 4 + i];
                b[i]     = Bs[k][tx * 4 + i];
                b[i + 4] = Bs[k][64 + tx * 4 + i];
            }
            #pragma unroll
            for (int i = 0; i < 8; ++i)
                #pragma unroll
                for (int j = 0; j < 8; ++j)
                    acc[i][j] += a[i] * b[j];
        }
        __syncthreads();
    }
    // bias (col mapping = split form)
    float bias[8];
    #pragma unroll
    for (int j = 0; j < 4; ++j) {
        bias[j]     = ldx(db, n0 + tx * 4 + j, f32);
        bias[j + 4] = ldx(db, n0 + 64 + tx * 4 + j, f32);
    }
    #pragma unroll
    for (int i = 0; i < 8; ++i)
        #pragma unroll
        for (int j = 0; j < 8; ++j)
            acc[i][j] += bias[j];

    // per-row tile max (red padded to 17 to avoid 32-way conflicts)
    __shared__ float red[DTM][17];
    __shared__ float mrow[DTM];
    #pragma unroll
    for (int i = 0; i < 8; ++i) {
        float mx = acc[i][0];
        #pragma unroll
        for (int j = 1; j < 8; ++j) mx = fmaxf(mx, acc[i][j]);
        red[dg_row(ty, i)][tx] = mx;
    }
    __syncthreads();
    if (tid < DTM) {
        float mx = red[tid][0];
        #pragma unroll
        for (int t = 1; t < 16; ++t) mx = fmaxf(mx, red[tid][t]);
        mrow[tid] = mx;
    }
    __syncthreads();
    // per-row tile sumexp
    #pragma unroll
    for (int i = 0; i < 8; ++i) {
        float m_ = mrow[dg_row(ty, i)];
        float s = 0.f;
        #pragma unroll
        for (int j = 0; j < 8; ++j) s += expf(acc[i][j] - m_);
        red[dg_row(ty, i)][tx] = s;
    }
    __syncthreads();
    if (tid < DTM) {
        float s = red[tid][0];
        #pragma unroll
        for (int t = 1; t < 16; ++t) s += red[tid][t];
        int r = m0 + tid;
        pm[(size_t)r * cNVT + nt] = mrow[tid];
        ps[(size_t)r * cNVT + nt] = s;
    }
    // label logit capture — constant indices only (no scratch demotion)
    #pragma unroll
    for (int i = 0; i < 8; ++i) {
        int r = m0 + dg_row(ty, i);
        int lb = labels[r];
        #pragma unroll
        for (int j = 0; j < 8; ++j) {
            int col = n0 + tx * 4 + (j & 3) + ((j >> 2) << 6);
            if (lb == col) lab[r] = acc[i][j];
        }
    }
}

// ---------------------------------------------------------------------------
// combine per-chunk (max, sumexp) into logp[label] per row. One wave per row.
__global__ __launch_bounds__(64) void lse_reduce_kernel(
    const float* __restrict__ pm, const float* __restrict__ ps,
    const float* __restrict__ lab, const int* __restrict__ labels,
    float* __restrict__ logppart)
{
    int r = blockIdx.x;
    int tid = threadIdx.x;
    if (labels[r] < 0) {
        if (tid == 0) logppart[r] = 0.f;
        return;
    }
    float m = -1e30f;
    for (int c = tid; c < cNVT; c += 64) m = fmaxf(m, pm[(size_t)r * cNVT + c]);
    for (int off = 32; off > 0; off >>= 1) m = fmaxf(m, __shfl_down(m, off));
    m = __shfl(m, 0);
    float s = 0.f;
    for (int c = tid; c < cNVT; c += 64)
        s += ps[(size_t)r * cNVT + c] * expf(pm[(size_t)r * cNVT + c] - m);
    for (int off = 32; off > 0; off >>= 1) s += __shfl_down(s, off);
    if (tid == 0) logppart[r] = lab[r] - (m + logf(s));
}

// ---------------------------------------------------------------------------
__global__ __launch_bounds__(256) void finalize_kernel(
    const float* __restrict__ velpart, const float* __restrict__ logppart,
    const int* __restrict__ wstart, const int* __restrict__ wend,
    void* __restrict__ out, const int* __restrict__ dflag)
{
    const int f32 = *dflag;
    __shared__ float r1[256], r2[256];
    int tid = threadIdx.x;
    float s1 = 0.f, s2 = 0.f;
    for (int r = tid; r < cB * cWIN; r += 256) {
        s1 += velpart[r];
        s2 += logppart[r];
    }
    r1[tid] = s1; r2[tid] = s2; __syncthreads();
    for (int off = 128; off > 0; off >>= 1) {
        if (tid < off) { r1[tid] += r1[tid + off]; r2[tid] += r2[tid + off]; }
        __syncthreads();
    }
    if (tid == 0) {
        float cnt = 0.f;
        for (int b = 0; b < cB; ++b)
            cnt += (float)min(max(wend[b] - wstart[b], 0), cWIN);
        cnt = fmaxf(cnt, 1.f);
        float vel = r1[0] / (cnt * (float)cD);
        float recon = -r2[0] / cnt;
        float loss = vel + cRECON_W * recon;
        if (f32) ((float*)out)[0] = loss;
        else     ((bf16*)out)[0] = __float2bfloat16(loss);
    }
}

// ===========================================================================
extern "C" void kernel_launch(void* const* d_in, const int* in_sizes, int n_in,
                              void* d_out, int out_size, void* d_ws, size_t ws_size,
                              hipStream_t stream) {
    const int*  token_ids    = (const int*)d_in[0];
    const int*  motif_ids    = (const int*)d_in[1];
    const int*  motif_len    = (const int*)d_in[2];
    const int*  window_start = (const int*)d_in[3];
    const int*  window_end   = (const int*)d_in[4];
    const void* t_arr        = d_in[5];
    const void* x0           = d_in[6];
    const void* embed_table  = d_in[7];
    const void* decode_W     = d_in[8];
    const void* decode_b     = d_in[9];
    const void* adapter_W    = d_in[10];
    const void* adapter_b    = d_in[11];
    const void* time_proj_W  = d_in[12];
    const void* time_proj_b  = d_in[13];
    const void* cond_proj_W  = d_in[14];
    const void* cond_proj_b  = d_in[15];
    const void* qkv_W        = d_in[16];
    const void* qkv_b        = d_in[17];
    const void* attn_out_W   = d_in[18];
    const void* attn_out_b   = d_in[19];
    const void* ff1_W        = d_in[20];
    const void* ff1_b        = d_in[21];
    const void* ff2_W        = d_in[22];
    const void* ff2_b        = d_in[23];
    const void* ln1_g        = d_in[24];
    const void* ln1_b        = d_in[25];
    const void* ln2_g        = d_in[26];
    const void* ln2_b        = d_in[27];
    const void* out_W        = d_in[28];
    const void* out_b        = d_in[29];

    float* w = (float*)d_ws;
    const size_t SZ_X   = (size_t)cB * cS * cD;
    const size_t SZ_BA  = (size_t)cB * cS * cFF;     // 4.23M floats
    const size_t SZ_ROW = (size_t)cB * cWIN * cD;
    float* x     = w;
    float* bufA  = x + SZ_X;
    float* bufB  = bufA + SZ_BA;
    float* bufC  = bufB + SZ_X;
    float* x1b   = bufC + SZ_X;
    float* xtb   = x1b + SZ_ROW;
    float* pvb   = xtb + SZ_ROW;
    float* h2b   = pvb + SZ_ROW;
    float* motif = h2b + SZ_ROW;
    float* left  = motif + (size_t)cB * cD;
    float* right = left + (size_t)cB * cD;
    float* glob  = right + (size_t)cB * cD;
    float* cond  = glob + (size_t)cB * cD;
    float* temb  = cond + (size_t)cB * cD;
    float* velpart = temb + (size_t)cB * cD;
    float* logppart = velpart + (size_t)cB * cWIN;
    int*   dflag = (int*)(logppart + (size_t)cB * cWIN);

    // decode partials live in bufA (free after the FF layers)
    const int Wrows = cB * cWIN;                      // 2048
    float* pm  = bufA;                                // [2048 * 250]
    float* ps  = pm + (size_t)Wrows * cNVT;           // [2048 * 250]
    float* lab = ps + (size_t)Wrows * cNVT;           // [2048]
    int*   labels = (int*)(lab + Wrows);              // [2048]

    const int Mrows = cB * cS;                        // 2064

    detect_kernel<<<1, 256, 0, stream>>>(x0, dflag);
    pools_kernel<<<cB, cD, 0, stream>>>(token_ids, motif_ids, motif_len,
        window_start, window_end, embed_table, left, right, glob, motif, dflag);
    cond_temb_kernel<<<cB, cD, 0, stream>>>(motif, left, right, glob, t_arr,
        cond_proj_W, cond_proj_b, time_proj_W, time_proj_b, cond, temb, dflag);
    build_x_kernel<<<Mrows, cD, 0, stream>>>(token_ids, window_start, window_end,
        t_arr, x0, embed_table, cond, temb, x, x1b, xtb, dflag);

    auto gemm = [&](const float* A, const void* W, size_t wOff,
                    const void* bias, size_t bOff, float* C,
                    int M_, int N_, int K_, int relu) {
        dim3 grid((N_ + TSN - 1) / TSN, (M_ + TSM - 1) / TSM);
        gemm_nt<<<grid, 256, 0, stream>>>(A, W, wOff, bias, bOff, C,
                                          M_, N_, K_, relu, dflag);
    };

    for (int i = 0; i < cNL; ++i) {
        gemm(x, qkv_W, (size_t)i * 3 * cD * cD, qkv_b, (size_t)i * 3 * cD,
             bufA, Mrows, 3 * cD, cD, 0);
        attn_kernel<<<dim3(cS, cH, cB), 128, 0, stream>>>(bufA, bufB);
        gemm(bufB, attn_out_W, (size_t)i * cD * cD, attn_out_b, (size_t)i * cD,
             bufC, Mrows, cD, cD, 0);
        resid_ln_kernel<<<Mrows, 256, 0, stream>>>(x, bufC, ln1_g, ln1_b,
             (size_t)i * cD, dflag);
        gemm(x, ff1_W, (size_t)i * cFF * cD, ff1_b, (size_t)i * cFF,
             bufA, Mrows, cFF, cD, 1);
        gemm(bufA, ff2_W, (size_t)i * cD * cFF, ff2_b, (size_t)i * cD,
             bufC, Mrows, cD, cFF, 0);
        resid_ln_kernel<<<Mrows, 256, 0, stream>>>(x, bufC, ln2_g, ln2_b,
             (size_t)i * cD, dflag);
    }

    copy_xs_kernel<<<Wrows, cD, 0, stream>>>(x, bufC);
    gemm(bufC, out_W, 0, out_b, 0, pvb, Wrows, cD, cD, 0);
    vel_kernel<<<Wrows, 256, 0, stream>>>(pvb, x1b, x0, window_start, window_end,
        velpart, dflag);
    predx1_kernel<<<Wrows, cD, 0, stream>>>(xtb, pvb, t_arr, bufC, dflag);
    gemm(bufC, adapter_W, 0, adapter_b, 0, h2b, Wrows, cD, cD, 0);

    // decode: labels -> tiled GEMM + partial LSE -> per-row reduce
    labels_kernel<<<(Wrows + 255) / 256, 256, 0, stream>>>(
        token_ids, window_start, window_end, labels);
    decode_gemm_kernel<<<dim3(cNVT, Wrows / DTM), 256, 0, stream>>>(
        h2b, decode_W, decode_b, labels, pm, ps, lab, dflag);
    lse_reduce_kernel<<<Wrows, 64, 0, stream>>>(pm, ps, lab, labels, logppart);

    finalize_kernel<<<1, 256, 0, stream>>>(velpart, logppart,
        window_start, window_end, d_out, dflag);
}

// Round 6
// 3686.155 us; speedup vs baseline: 8.9150x; 1.3863x over previous
//
#include <hip/hip_runtime.h>
#include <hip/hip_bf16.h>
#include <math.h>

typedef __hip_bfloat16 bf16;

// Problem constants
constexpr int cB = 16, cL = 2048, cWIN = 128, cD = 512, cH = 8, cFF = 2048;
constexpr int cNL = 3, cV = 32000, cM = 32;
constexpr int cHD = cD / cH;     // 64
constexpr int cS = cWIN + 1;     // 129
constexpr float cEPS = 1e-5f;
constexpr float cRECON_W = 0.1f;
constexpr int cNVT = cV / 128;   // 250 vocab tiles

__device__ __forceinline__ float b2f(bf16 x) { return __bfloat162float(x); }

// dtype-agnostic load with ELEMENT offset: f32 flag selects interpretation.
__device__ __forceinline__ float ldx(const void* p, size_t i, int f32) {
    return f32 ? ((const float*)p)[i]
               : __bfloat162float(((const bf16*)p)[i]);
}

// f32 -> bf16 bits, round-to-nearest-even (self-contained, no type issues)
__device__ __forceinline__ unsigned short f2bf(float f) {
    union { float f; unsigned int u; } v; v.f = f;
    unsigned int u = v.u + 0x7FFFu + ((v.u >> 16) & 1u);
    return (unsigned short)(u >> 16);
}

// MFMA fragment types (guide §3: short8 = 8 bf16 = 4 VGPRs; float4 acc)
typedef short bf16x8 __attribute__((ext_vector_type(8)));
typedef float f32x4  __attribute__((ext_vector_type(4)));

// ---------------------------------------------------------------------------
// dtype detection: x0 ~ N(0,1). bf16 data: all halfwords decode |v|<128.
// float32 data: even halfwords are low mantissa bits -> ~47% decode |v|>=128.
__global__ void detect_kernel(const void* __restrict__ x0raw, int* __restrict__ flag)
{
    const unsigned short* h = (const unsigned short*)x0raw;
    int tid = threadIdx.x;
    int cnt = 0;
    for (int j = tid; j < 8192; j += 256) {
        unsigned short u = h[2 * j];
        int e = (u >> 7) & 0xFF;
        if (e >= 134) cnt++;
    }
    __shared__ int red[256];
    red[tid] = cnt; __syncthreads();
    for (int off = 128; off > 0; off >>= 1) {
        if (tid < off) red[tid] += red[tid + off];
        __syncthreads();
    }
    if (tid == 0) *flag = (red[0] > 400) ? 1 : 0;
}

// ---------------------------------------------------------------------------
// pools split over L chunks for parallelism: grid (8 chunks, 16 batches)
__global__ __launch_bounds__(512) void pools_part_kernel(
    const int* __restrict__ tok, const int* __restrict__ wstart,
    const int* __restrict__ wend, const void* __restrict__ emb,
    float* __restrict__ part, const int* __restrict__ dflag)
{
    const int f32 = *dflag;
    int chunk = blockIdx.x;          // 0..7
    int b = blockIdx.y;              // 0..15
    int d = threadIdx.x;             // 0..511
    int ws_ = wstart[b], we_ = wend[b];
    float sl = 0.f, sr = 0.f, sg = 0.f;
    int l0 = chunk * 256;
    for (int l = l0; l < l0 + 256; ++l) {
        int t = tok[b * cL + l];
        float h = ldx(emb, (size_t)t * cD + d, f32);
        sg += h;
        if (l < ws_) sl += h;
        if (l >= we_) sr += h;
    }
    size_t base = ((size_t)(b * 8 + chunk)) * 3 * cD;
    part[base + d]            = sl;
    part[base + cD + d]       = sr;
    part[base + 2 * cD + d]   = sg;
}

__global__ __launch_bounds__(512) void pools_combine_kernel(
    const float* __restrict__ part, const int* __restrict__ mids,
    const int* __restrict__ mlen, const int* __restrict__ wstart,
    const int* __restrict__ wend, const void* __restrict__ emb,
    float* __restrict__ left, float* __restrict__ right,
    float* __restrict__ glob, float* __restrict__ motif,
    const int* __restrict__ dflag)
{
    const int f32 = *dflag;
    int b = blockIdx.x;
    int d = threadIdx.x;
    int ws_ = wstart[b], we_ = wend[b];
    float sl = 0.f, sr = 0.f, sg = 0.f;
    for (int c = 0; c < 8; ++c) {
        size_t base = ((size_t)(b * 8 + c)) * 3 * cD;
        sl += part[base + d];
        sr += part[base + cD + d];
        sg += part[base + 2 * cD + d];
    }
    left[b * cD + d]  = sl / fmaxf((float)ws_, 1.f);
    right[b * cD + d] = sr / fmaxf((float)(cL - we_), 1.f);
    glob[b * cD + d]  = sg / (float)cL;
    int ml = mlen[b];
    float sm = 0.f;
    for (int j = 0; j < cM; ++j) {
        if (j < ml) sm += ldx(emb, (size_t)mids[b * cM + j] * cD + d, f32);
    }
    motif[b * cD + d] = sm / fmaxf((float)ml, 1.f);
}

// ---------------------------------------------------------------------------
__global__ __launch_bounds__(512) void cond_temb_kernel(
    const float* __restrict__ motif, const float* __restrict__ left,
    const float* __restrict__ right, const float* __restrict__ glob,
    const void* __restrict__ t_arr,
    const void* __restrict__ cond_W, const void* __restrict__ cond_b,
    const void* __restrict__ tp_W, const void* __restrict__ tp_b,
    float* __restrict__ cond, float* __restrict__ temb,
    const int* __restrict__ dflag)
{
    const int f32 = *dflag;
    __shared__ float feat[4 * cD];
    __shared__ float tf[cD];
    int b = blockIdx.x;
    int d = threadIdx.x;
    feat[d]          = motif[b * cD + d];
    feat[cD + d]     = left[b * cD + d];
    feat[2 * cD + d] = right[b * cD + d];
    feat[3 * cD + d] = glob[b * cD + d];
    float t = ldx(t_arr, b, f32);
    const int half = cD / 2;
    {
        int j = d;
        if (j < half) {
            float fr = expf(-logf(10000.f) * (float)j / (float)(half - 1));
            tf[j] = sinf(t * fr);
        } else {
            float fr = expf(-logf(10000.f) * (float)(j - half) / (float)(half - 1));
            tf[j] = cosf(t * fr);
        }
    }
    __syncthreads();
    float sc = 0.f;
    for (int k = 0; k < 4 * cD; ++k)
        sc += feat[k] * ldx(cond_W, (size_t)d * (4 * cD) + k, f32);
    cond[b * cD + d] = sc + ldx(cond_b, d, f32);
    float st = 0.f;
    for (int k = 0; k < cD; ++k)
        st += tf[k] * ldx(tp_W, (size_t)d * cD + k, f32);
    temb[b * cD + d] = st + ldx(tp_b, d, f32);
}

// ---------------------------------------------------------------------------
__global__ __launch_bounds__(512) void build_x_kernel(
    const int* __restrict__ tok, const int* __restrict__ wstart,
    const int* __restrict__ wend, const void* __restrict__ t_arr,
    const void* __restrict__ x0, const void* __restrict__ emb,
    const float* __restrict__ cond, const float* __restrict__ temb,
    float* __restrict__ x, float* __restrict__ x1, float* __restrict__ xt,
    const int* __restrict__ dflag)
{
    const int f32 = *dflag;
    int row = blockIdx.x;
    int b = row / cS, s = row % cS;
    int d = threadIdx.x;
    if (s == 0) { x[(size_t)row * cD + d] = cond[b * cD + d]; return; }
    int i = s - 1;
    int ws_ = wstart[b], we_ = wend[b];
    int actual = min(max(we_ - ws_, 0), cWIN);
    int idx = min(ws_ + i, cL - 1);
    float x1v = 0.f;
    if (i < actual) x1v = ldx(emb, (size_t)tok[b * cL + idx] * cD + d, f32);
    float t = ldx(t_arr, b, f32);
    float x0v = ldx(x0, ((size_t)b * cWIN + i) * cD + d, f32);
    float xtv = (1.f - t) * x0v + t * x1v;
    size_t ro = ((size_t)b * cWIN + i) * cD + d;
    x1[ro] = x1v;
    xt[ro] = xtv;
    x[(size_t)row * cD + d] = xtv + temb[b * cD + d];
}

// ---------------------------------------------------------------------------
// MFMA GEMM: C[M,N] = A[M,K] @ W[N,K]^T + bias (+relu).
// A fp32 workspace; W/bias flagged dtype with element offsets.
// 128x128 tile, BK=32, 4 waves, each wave = 64x64 (4x4 mfma_f32_16x16x32_bf16).
// A- and B-fragments: lane reads 8 contiguous bf16 at row (lane&15),
// k-off (lane>>4)*8 [m89/m120-verified]. C/D: col=lane&15, row=quad*4+reg.
// LDS row stride 40 bf16 (80 B): 16B-aligned b128 reads, 2-way alias (free).
constexpr int GBM = 128, GBN = 128, GBK = 32, GLDS = 40;
__global__ __launch_bounds__(256) void gemm_mfma(
    const float* __restrict__ A, const void* __restrict__ Wb, size_t wOff,
    const void* __restrict__ biasb, size_t bOff, float* __restrict__ C,
    int Mdim, int Ndim, int Kdim, int relu, const int* __restrict__ dflag)
{
    const int f32 = *dflag;
    const float* Wf = (const float*)Wb + wOff;     // used if f32
    const bf16*  Wh = (const bf16*)Wb + wOff;      // used if bf16
    __shared__ unsigned short As[GBM * GLDS];
    __shared__ unsigned short Bs[GBN * GLDS];
    const int tid = threadIdx.x;
    const int lane = tid & 63;
    const int wid = tid >> 6;          // 0..3
    const int wm = wid >> 1, wn = wid & 1;
    const int quad = lane >> 4, lm = lane & 15;
    const int m0 = blockIdx.y * GBM;
    const int n0 = blockIdx.x * GBN;

    f32x4 acc[4][4];
    #pragma unroll
    for (int i = 0; i < 4; ++i)
        #pragma unroll
        for (int j = 0; j < 4; ++j)
            acc[i][j] = (f32x4){0.f, 0.f, 0.f, 0.f};

    for (int k0 = 0; k0 < Kdim; k0 += GBK) {
        // stage A: 128 rows x 32 k as bf16 (guarded rows)
        #pragma unroll
        for (int t = 0; t < 4; ++t) {
            int chunk = tid + t * 256;          // 0..1023 (vec4 chunks)
            int row = chunk >> 3;
            int kc = (chunk & 7) * 4;
            int gr = m0 + row;
            float4 v = {0.f, 0.f, 0.f, 0.f};
            if (gr < Mdim)
                v = *(const float4*)(A + (size_t)gr * Kdim + k0 + kc);
            int o = row * GLDS + kc;
            As[o]     = f2bf(v.x);
            As[o + 1] = f2bf(v.y);
            As[o + 2] = f2bf(v.z);
            As[o + 3] = f2bf(v.w);
        }
        // stage W: 128 rows (n) x 32 k as bf16 (N always multiple of 128)
        #pragma unroll
        for (int t = 0; t < 4; ++t) {
            int chunk = tid + t * 256;
            int row = chunk >> 3;
            int kc = (chunk & 7) * 4;
            size_t gro = (size_t)(n0 + row) * Kdim + k0 + kc;
            int o = row * GLDS + kc;
            if (f32) {
                float4 v = *(const float4*)(Wf + gro);
                Bs[o]     = f2bf(v.x);
                Bs[o + 1] = f2bf(v.y);
                Bs[o + 2] = f2bf(v.z);
                Bs[o + 3] = f2bf(v.w);
            } else {
                Bs[o]     = f2bf(b2f(Wh[gro]));
                Bs[o + 1] = f2bf(b2f(Wh[gro + 1]));
                Bs[o + 2] = f2bf(b2f(Wh[gro + 2]));
                Bs[o + 3] = f2bf(b2f(Wh[gro + 3]));
            }
        }
        __syncthreads();
        // fragments + MFMA
        bf16x8 af[4], bfr[4];
        #pragma unroll
        for (int im = 0; im < 4; ++im) {
            int row = wm * 64 + im * 16 + lm;
            af[im] = *(const bf16x8*)(As + row * GLDS + quad * 8);
        }
        #pragma unroll
        for (int in = 0; in < 4; ++in) {
            int row = wn * 64 + in * 16 + lm;
            bfr[in] = *(const bf16x8*)(Bs + row * GLDS + quad * 8);
        }
        #pragma unroll
        for (int im = 0; im < 4; ++im)
            #pragma unroll
            for (int in = 0; in < 4; ++in)
                acc[im][in] = __builtin_amdgcn_mfma_f32_16x16x32_bf16(
                    af[im], bfr[in], acc[im][in], 0, 0, 0);
        __syncthreads();
    }

    // epilogue: bias + relu + guarded store
    #pragma unroll
    for (int in = 0; in < 4; ++in) {
        int gc = n0 + wn * 64 + in * 16 + lm;
        float bv = ldx(biasb, bOff + gc, f32);
        #pragma unroll
        for (int im = 0; im < 4; ++im) {
            #pragma unroll
            for (int r = 0; r < 4; ++r) {
                int gr = m0 + wm * 64 + im * 16 + quad * 4 + r;
                if (gr < Mdim) {
                    float v = acc[im][in][r] + bv;
                    if (relu) v = fmaxf(v, 0.f);
                    C[(size_t)gr * Ndim + gc] = v;
                }
            }
        }
    }
}

// ---------------------------------------------------------------------------
__global__ __launch_bounds__(128) void attn_kernel(
    const float* __restrict__ qkv, float* __restrict__ ctx)
{
    int s = blockIdx.x, h = blockIdx.y, b = blockIdx.z;
    __shared__ float qv[cHD];
    __shared__ float sc[cS];
    __shared__ float red[128];
    int tid = threadIdx.x;
    const float* base = qkv + (size_t)b * cS * (3 * cD);
    if (tid < cHD) qv[tid] = base[(size_t)s * (3 * cD) + h * cHD + tid];
    __syncthreads();
    for (int k = tid; k < cS; k += 128) {
        const float* kv = base + (size_t)k * (3 * cD) + cD + h * cHD;
        float dot = 0.f;
        #pragma unroll
        for (int e = 0; e < cHD; ++e) dot += qv[e] * kv[e];
        sc[k] = dot * 0.125f;
    }
    __syncthreads();
    float m = -1e30f;
    for (int k = tid; k < cS; k += 128) m = fmaxf(m, sc[k]);
    red[tid] = m; __syncthreads();
    for (int off = 64; off > 0; off >>= 1) {
        if (tid < off) red[tid] = fmaxf(red[tid], red[tid + off]);
        __syncthreads();
    }
    m = red[0];
    __syncthreads();
    float sum = 0.f;
    for (int k = tid; k < cS; k += 128) {
        float e = expf(sc[k] - m);
        sc[k] = e;
        sum += e;
    }
    red[tid] = sum; __syncthreads();
    for (int off = 64; off > 0; off >>= 1) {
        if (tid < off) red[tid] += red[tid + off];
        __syncthreads();
    }
    float inv = 1.f / red[0];
    if (tid < cHD) {
        float acc = 0.f;
        for (int k = 0; k < cS; ++k)
            acc += sc[k] * base[(size_t)k * (3 * cD) + 2 * cD + h * cHD + tid];
        ctx[((size_t)(b * cS + s)) * cD + h * cHD + tid] = acc * inv;
    }
}

// ---------------------------------------------------------------------------
__global__ __launch_bounds__(256) void resid_ln_kernel(
    float* __restrict__ x, const float* __restrict__ h,
    const void* __restrict__ g, const void* __restrict__ bta, size_t off,
    const int* __restrict__ dflag)
{
    const int f32 = *dflag;
    int row = blockIdx.x;
    int tid = threadIdx.x;
    __shared__ float red[256];
    float v[2];
    float s = 0.f;
    #pragma unroll
    for (int j = 0; j < 2; ++j) {
        int d = tid + j * 256;
        v[j] = x[(size_t)row * cD + d] + h[(size_t)row * cD + d];
        s += v[j];
    }
    red[tid] = s; __syncthreads();
    for (int o = 128; o > 0; o >>= 1) {
        if (tid < o) red[tid] += red[tid + o];
        __syncthreads();
    }
    float mean = red[0] / (float)cD;
    __syncthreads();
    float vs = 0.f;
    #pragma unroll
    for (int j = 0; j < 2; ++j) { float dd = v[j] - mean; vs += dd * dd; }
    red[tid] = vs; __syncthreads();
    for (int o = 128; o > 0; o >>= 1) {
        if (tid < o) red[tid] += red[tid + o];
        __syncthreads();
    }
    float rs = rsqrtf(red[0] / (float)cD + cEPS);
    #pragma unroll
    for (int j = 0; j < 2; ++j) {
        int d = tid + j * 256;
        x[(size_t)row * cD + d] = (v[j] - mean) * rs * ldx(g, off + d, f32)
                                  + ldx(bta, off + d, f32);
    }
}

// ---------------------------------------------------------------------------
__global__ __launch_bounds__(512) void copy_xs_kernel(
    const float* __restrict__ x, float* __restrict__ xs)
{
    int row = blockIdx.x;
    int b = row / cWIN, i = row % cWIN;
    int d = threadIdx.x;
    xs[(size_t)row * cD + d] = x[((size_t)(b * cS + 1 + i)) * cD + d];
}

// ---------------------------------------------------------------------------
__global__ __launch_bounds__(256) void vel_kernel(
    const float* __restrict__ pv, const float* __restrict__ x1,
    const void* __restrict__ x0, const int* __restrict__ wstart,
    const int* __restrict__ wend, float* __restrict__ velpart,
    const int* __restrict__ dflag)
{
    const int f32 = *dflag;
    int row = blockIdx.x;
    int b = row / cWIN, i = row % cWIN;
    int tid = threadIdx.x;
    int actual = min(max(wend[b] - wstart[b], 0), cWIN);
    if (i >= actual) {
        if (tid == 0) velpart[row] = 0.f;
        return;
    }
    __shared__ float red[256];
    float s = 0.f;
    for (int d = tid; d < cD; d += 256) {
        size_t o = (size_t)row * cD + d;
        float tv = x1[o] - ldx(x0, o, f32);
        float diff = pv[o] - tv;
        s += diff * diff;
    }
    red[tid] = s; __syncthreads();
    for (int off = 128; off > 0; off >>= 1) {
        if (tid < off) red[tid] += red[tid + off];
        __syncthreads();
    }
    if (tid == 0) velpart[row] = red[0];
}

// ---------------------------------------------------------------------------
__global__ __launch_bounds__(512) void predx1_kernel(
    const float* __restrict__ xt, const float* __restrict__ pv,
    const void* __restrict__ t_arr, float* __restrict__ outp,
    const int* __restrict__ dflag)
{
    const int f32 = *dflag;
    int row = blockIdx.x;
    int b = row / cWIN;
    int d = threadIdx.x;
    float t = ldx(t_arr, b, f32);
    size_t o = (size_t)row * cD + d;
    outp[o] = xt[o] + (1.f - t) * pv[o];
}

// ---------------------------------------------------------------------------
__global__ void labels_kernel(
    const int* __restrict__ tok, const int* __restrict__ wstart,
    const int* __restrict__ wend, int* __restrict__ labels)
{
    int r = blockIdx.x * 256 + threadIdx.x;
    if (r >= cB * cWIN) return;
    int b = r / cWIN, i = r % cWIN;
    int ws_ = wstart[b], we_ = wend[b];
    int actual = min(max(we_ - ws_, 0), cWIN);
    labels[r] = (i < actual) ? tok[b * cL + min(ws_ + i, cL - 1)] : -1;
}

// ---------------------------------------------------------------------------
// decode tiled fp32 GEMM + fused partial log-sum-exp (proven R5: 58 TF).
constexpr int DTM = 128, DTN = 128, DTK = 8;
__device__ __forceinline__ int dg_row(int ty, int i) {
    return ty * 4 + (i & 3) + ((i >> 2) << 6);
}
__global__ __launch_bounds__(256) void decode_gemm_kernel(
    const float* __restrict__ H, const void* __restrict__ dW,
    const void* __restrict__ db, const int* __restrict__ labels,
    float* __restrict__ pm, float* __restrict__ ps, float* __restrict__ lab,
    const int* __restrict__ dflag)
{
    const int f32 = *dflag;
    const int nt = blockIdx.x;
    const int mt = blockIdx.y;
    const int m0 = mt * DTM, n0 = nt * DTN;
    __shared__ float As[DTK][DTM + 4];
    __shared__ float Bs[DTK][DTN + 4];
    const int tid = threadIdx.x;
    const int tx = tid & 15, ty = tid >> 4;
    float acc[8][8] = {};
    for (int k0 = 0; k0 < cD; k0 += DTK) {
        #pragma unroll
        for (int t = 0; t < 4; ++t) {
            int idx = tid + t * 256;
            int m = idx >> 3, k = idx & 7;
            As[k][m] = H[(size_t)(m0 + m) * cD + k0 + k];
        }
        #pragma unroll
        for (int t = 0; t < 4; ++t) {
            int idx = tid + t * 256;
            int n = idx >> 3, k = idx & 7;
            Bs[k][n] = ldx(dW, (size_t)(n0 + n) * cD + k0 + k, f32);
        }
        __syncthreads();
        #pragma unroll
        for (int k = 0; k < DTK; ++k) {
            float a[8], b[8];
            #pragma unroll
            for (int i = 0; i < 4; ++i) {
                a[i]     = As[k][ty * 4 + i];
                a[i + 4] = As[k][64 + ty * 4 + i];
                b[i]     = Bs[k][tx * 4 + i];
                b[i + 4] = Bs[k][64 + tx * 4 + i];
            }
            #pragma unroll
            for (int i = 0; i < 8; ++i)
                #pragma unroll
                for (int j = 0; j < 8; ++j)
                    acc[i][j] += a[i] * b[j];
        }
        __syncthreads();
    }
    float bias[8];
    #pragma unroll
    for (int j = 0; j < 4; ++j) {
        bias[j]     = ldx(db, n0 + tx * 4 + j, f32);
        bias[j + 4] = ldx(db, n0 + 64 + tx * 4 + j, f32);
    }
    #pragma unroll
    for (int i = 0; i < 8; ++i)
        #pragma unroll
        for (int j = 0; j < 8; ++j)
            acc[i][j] += bias[j];

    __shared__ float red[DTM][17];
    __shared__ float mrow[DTM];
    #pragma unroll
    for (int i = 0; i < 8; ++i) {
        float mx = acc[i][0];
        #pragma unroll
        for (int j = 1; j < 8; ++j) mx = fmaxf(mx, acc[i][j]);
        red[dg_row(ty, i)][tx] = mx;
    }
    __syncthreads();
    if (tid < DTM) {
        float mx = red[tid][0];
        #pragma unroll
        for (int t = 1; t < 16; ++t) mx = fmaxf(mx, red[tid][t]);
        mrow[tid] = mx;
    }
    __syncthreads();
    #pragma unroll
    for (int i = 0; i < 8; ++i) {
        float m_ = mrow[dg_row(ty, i)];
        float s = 0.f;
        #pragma unroll
        for (int j = 0; j < 8; ++j) s += expf(acc[i][j] - m_);
        red[dg_row(ty, i)][tx] = s;
    }
    __syncthreads();
    if (tid < DTM) {
        float s = red[tid][0];
        #pragma unroll
        for (int t = 1; t < 16; ++t) s += red[tid][t];
        int r = m0 + tid;
        pm[(size_t)r * cNVT + nt] = mrow[tid];
        ps[(size_t)r * cNVT + nt] = s;
    }
    #pragma unroll
    for (int i = 0; i < 8; ++i) {
        int r = m0 + dg_row(ty, i);
        int lb = labels[r];
        #pragma unroll
        for (int j = 0; j < 8; ++j) {
            int col = n0 + tx * 4 + (j & 3) + ((j >> 2) << 6);
            if (lb == col) lab[r] = acc[i][j];
        }
    }
}

// ---------------------------------------------------------------------------
__global__ __launch_bounds__(64) void lse_reduce_kernel(
    const float* __restrict__ pm, const float* __restrict__ ps,
    const float* __restrict__ lab, const int* __restrict__ labels,
    float* __restrict__ logppart)
{
    int r = blockIdx.x;
    int tid = threadIdx.x;
    if (labels[r] < 0) {
        if (tid == 0) logppart[r] = 0.f;
        return;
    }
    float m = -1e30f;
    for (int c = tid; c < cNVT; c += 64) m = fmaxf(m, pm[(size_t)r * cNVT + c]);
    for (int off = 32; off > 0; off >>= 1) m = fmaxf(m, __shfl_down(m, off));
    m = __shfl(m, 0);
    float s = 0.f;
    for (int c = tid; c < cNVT; c += 64)
        s += ps[(size_t)r * cNVT + c] * expf(pm[(size_t)r * cNVT + c] - m);
    for (int off = 32; off > 0; off >>= 1) s += __shfl_down(s, off);
    if (tid == 0) logppart[r] = lab[r] - (m + logf(s));
}

// ---------------------------------------------------------------------------
__global__ __launch_bounds__(256) void finalize_kernel(
    const float* __restrict__ velpart, const float* __restrict__ logppart,
    const int* __restrict__ wstart, const int* __restrict__ wend,
    void* __restrict__ out, const int* __restrict__ dflag)
{
    const int f32 = *dflag;
    __shared__ float r1[256], r2[256];
    int tid = threadIdx.x;
    float s1 = 0.f, s2 = 0.f;
    for (int r = tid; r < cB * cWIN; r += 256) {
        s1 += velpart[r];
        s2 += logppart[r];
    }
    r1[tid] = s1; r2[tid] = s2; __syncthreads();
    for (int off = 128; off > 0; off >>= 1) {
        if (tid < off) { r1[tid] += r1[tid + off]; r2[tid] += r2[tid + off]; }
        __syncthreads();
    }
    if (tid == 0) {
        float cnt = 0.f;
        for (int b = 0; b < cB; ++b)
            cnt += (float)min(max(wend[b] - wstart[b], 0), cWIN);
        cnt = fmaxf(cnt, 1.f);
        float vel = r1[0] / (cnt * (float)cD);
        float recon = -r2[0] / cnt;
        float loss = vel + cRECON_W * recon;
        if (f32) ((float*)out)[0] = loss;
        else     ((bf16*)out)[0] = __float2bfloat16(loss);
    }
}

// ===========================================================================
extern "C" void kernel_launch(void* const* d_in, const int* in_sizes, int n_in,
                              void* d_out, int out_size, void* d_ws, size_t ws_size,
                              hipStream_t stream) {
    const int*  token_ids    = (const int*)d_in[0];
    const int*  motif_ids    = (const int*)d_in[1];
    const int*  motif_len    = (const int*)d_in[2];
    const int*  window_start = (const int*)d_in[3];
    const int*  window_end   = (const int*)d_in[4];
    const void* t_arr        = d_in[5];
    const void* x0           = d_in[6];
    const void* embed_table  = d_in[7];
    const void* decode_W     = d_in[8];
    const void* decode_b     = d_in[9];
    const void* adapter_W    = d_in[10];
    const void* adapter_b    = d_in[11];
    const void* time_proj_W  = d_in[12];
    const void* time_proj_b  = d_in[13];
    const void* cond_proj_W  = d_in[14];
    const void* cond_proj_b  = d_in[15];
    const void* qkv_W        = d_in[16];
    const void* qkv_b        = d_in[17];
    const void* attn_out_W   = d_in[18];
    const void* attn_out_b   = d_in[19];
    const void* ff1_W        = d_in[20];
    const void* ff1_b        = d_in[21];
    const void* ff2_W        = d_in[22];
    const void* ff2_b        = d_in[23];
    const void* ln1_g        = d_in[24];
    const void* ln1_b        = d_in[25];
    const void* ln2_g        = d_in[26];
    const void* ln2_b        = d_in[27];
    const void* out_W        = d_in[28];
    const void* out_b        = d_in[29];

    float* w = (float*)d_ws;
    const size_t SZ_X   = (size_t)cB * cS * cD;
    const size_t SZ_BA  = (size_t)cB * cS * cFF;
    const size_t SZ_ROW = (size_t)cB * cWIN * cD;
    float* x     = w;
    float* bufA  = x + SZ_X;
    float* bufB  = bufA + SZ_BA;
    float* bufC  = bufB + SZ_X;
    float* x1b   = bufC + SZ_X;
    float* xtb   = x1b + SZ_ROW;
    float* pvb   = xtb + SZ_ROW;
    float* h2b   = pvb + SZ_ROW;
    float* motif = h2b + SZ_ROW;
    float* left  = motif + (size_t)cB * cD;
    float* right = left + (size_t)cB * cD;
    float* glob  = right + (size_t)cB * cD;
    float* cond  = glob + (size_t)cB * cD;
    float* temb  = cond + (size_t)cB * cD;
    float* velpart = temb + (size_t)cB * cD;
    float* logppart = velpart + (size_t)cB * cWIN;
    int*   dflag = (int*)(logppart + (size_t)cB * cWIN);

    const int Wrows = cB * cWIN;                      // 2048
    float* pm  = bufA;                                // decode partials in bufA
    float* ps  = pm + (size_t)Wrows * cNVT;
    float* lab = ps + (size_t)Wrows * cNVT;
    int*   labels = (int*)(lab + Wrows);
    float* poolspart = bufC;                          // pools partials in bufC

    const int Mrows = cB * cS;                        // 2064

    detect_kernel<<<1, 256, 0, stream>>>(x0, dflag);
    pools_part_kernel<<<dim3(8, cB), cD, 0, stream>>>(token_ids, window_start,
        window_end, embed_table, poolspart, dflag);
    pools_combine_kernel<<<cB, cD, 0, stream>>>(poolspart, motif_ids, motif_len,
        window_start, window_end, embed_table, left, right, glob, motif, dflag);
    cond_temb_kernel<<<cB, cD, 0, stream>>>(motif, left, right, glob, t_arr,
        cond_proj_W, cond_proj_b, time_proj_W, time_proj_b, cond, temb, dflag);
    build_x_kernel<<<Mrows, cD, 0, stream>>>(token_ids, window_start, window_end,
        t_arr, x0, embed_table, cond, temb, x, x1b, xtb, dflag);

    auto gemm = [&](const float* A, const void* W, size_t wOff,
                    const void* bias, size_t bOff, float* C,
                    int M_, int N_, int K_, int relu) {
        dim3 grid(N_ / GBN, (M_ + GBM - 1) / GBM);
        gemm_mfma<<<grid, 256, 0, stream>>>(A, W, wOff, bias, bOff, C,
                                            M_, N_, K_, relu, dflag);
    };

    for (int i = 0; i < cNL; ++i) {
        gemm(x, qkv_W, (size_t)i * 3 * cD * cD, qkv_b, (size_t)i * 3 * cD,
             bufA, Mrows, 3 * cD, cD, 0);
        attn_kernel<<<dim3(cS, cH, cB), 128, 0, stream>>>(bufA, bufB);
        gemm(bufB, attn_out_W, (size_t)i * cD * cD, attn_out_b, (size_t)i * cD,
             bufC, Mrows, cD, cD, 0);
        resid_ln_kernel<<<Mrows, 256, 0, stream>>>(x, bufC, ln1_g, ln1_b,
             (size_t)i * cD, dflag);
        gemm(x, ff1_W, (size_t)i * cFF * cD, ff1_b, (size_t)i * cFF,
             bufA, Mrows, cFF, cD, 1);
        gemm(bufA, ff2_W, (size_t)i * cD * cFF, ff2_b, (size_t)i * cD,
             bufC, Mrows, cD, cFF, 0);
        resid_ln_kernel<<<Mrows, 256, 0, stream>>>(x, bufC, ln2_g, ln2_b,
             (size_t)i * cD, dflag);
    }

    copy_xs_kernel<<<Wrows, cD, 0, stream>>>(x, bufC);
    gemm(bufC, out_W, 0, out_b, 0, pvb, Wrows, cD, cD, 0);
    vel_kernel<<<Wrows, 256, 0, stream>>>(pvb, x1b, x0, window_start, window_end,
        velpart, dflag);
    predx1_kernel<<<Wrows, cD, 0, stream>>>(xtb, pvb, t_arr, bufC, dflag);
    gemm(bufC, adapter_W, 0, adapter_b, 0, h2b, Wrows, cD, cD, 0);

    labels_kernel<<<(Wrows + 255) / 256, 256, 0, stream>>>(
        token_ids, window_start, window_end, labels);
    decode_gemm_kernel<<<dim3(cNVT, Wrows / DTM), 256, 0, stream>>>(
        h2b, decode_W, decode_b, labels, pm, ps, lab, dflag);
    lse_reduce_kernel<<<Wrows, 64, 0, stream>>>(pm, ps, lab, labels, logppart);

    finalize_kernel<<<1, 256, 0, stream>>>(velpart, logppart,
        window_start, window_end, d_out, dflag);
}

// Round 7
// 2583.192 us; speedup vs baseline: 12.7215x; 1.4270x over previous
//
#include <hip/hip_runtime.h>
#include <hip/hip_bf16.h>
#include <math.h>

typedef __hip_bfloat16 bf16;

// Problem constants
constexpr int cB = 16, cL = 2048, cWIN = 128, cD = 512, cH = 8, cFF = 2048;
constexpr int cNL = 3, cV = 32000, cM = 32;
constexpr int cHD = cD / cH;     // 64
constexpr int cS = cWIN + 1;     // 129
constexpr float cEPS = 1e-5f;
constexpr float cRECON_W = 0.1f;
constexpr int cNVT = cV / 128;   // 250 vocab tiles

__device__ __forceinline__ float b2f(bf16 x) { return __bfloat162float(x); }

// dtype-agnostic load with ELEMENT offset: f32 flag selects interpretation.
__device__ __forceinline__ float ldx(const void* p, size_t i, int f32) {
    return f32 ? ((const float*)p)[i]
               : __bfloat162float(((const bf16*)p)[i]);
}

// f32 -> bf16 bits, round-to-nearest-even
__device__ __forceinline__ unsigned short f2bf(float f) {
    union { float f; unsigned int u; } v; v.f = f;
    unsigned int u = v.u + 0x7FFFu + ((v.u >> 16) & 1u);
    return (unsigned short)(u >> 16);
}

// MFMA fragment types
typedef short bf16x8 __attribute__((ext_vector_type(8)));
typedef float f32x4  __attribute__((ext_vector_type(4)));

// ---------------------------------------------------------------------------
__global__ void detect_kernel(const void* __restrict__ x0raw, int* __restrict__ flag)
{
    const unsigned short* h = (const unsigned short*)x0raw;
    int tid = threadIdx.x;
    int cnt = 0;
    for (int j = tid; j < 8192; j += 256) {
        unsigned short u = h[2 * j];
        int e = (u >> 7) & 0xFF;
        if (e >= 134) cnt++;
    }
    __shared__ int red[256];
    red[tid] = cnt; __syncthreads();
    for (int off = 128; off > 0; off >>= 1) {
        if (tid < off) red[tid] += red[tid + off];
        __syncthreads();
    }
    if (tid == 0) *flag = (red[0] > 400) ? 1 : 0;
}

// ---------------------------------------------------------------------------
__global__ __launch_bounds__(512) void pools_part_kernel(
    const int* __restrict__ tok, const int* __restrict__ wstart,
    const int* __restrict__ wend, const void* __restrict__ emb,
    float* __restrict__ part, const int* __restrict__ dflag)
{
    const int f32 = *dflag;
    int chunk = blockIdx.x;          // 0..7
    int b = blockIdx.y;              // 0..15
    int d = threadIdx.x;             // 0..511
    int ws_ = wstart[b], we_ = wend[b];
    float sl = 0.f, sr = 0.f, sg = 0.f;
    int l0 = chunk * 256;
    for (int l = l0; l < l0 + 256; ++l) {
        int t = tok[b * cL + l];
        float h = ldx(emb, (size_t)t * cD + d, f32);
        sg += h;
        if (l < ws_) sl += h;
        if (l >= we_) sr += h;
    }
    size_t base = ((size_t)(b * 8 + chunk)) * 3 * cD;
    part[base + d]            = sl;
    part[base + cD + d]       = sr;
    part[base + 2 * cD + d]   = sg;
}

__global__ __launch_bounds__(512) void pools_combine_kernel(
    const float* __restrict__ part, const int* __restrict__ mids,
    const int* __restrict__ mlen, const int* __restrict__ wstart,
    const int* __restrict__ wend, const void* __restrict__ emb,
    float* __restrict__ left, float* __restrict__ right,
    float* __restrict__ glob, float* __restrict__ motif,
    const int* __restrict__ dflag)
{
    const int f32 = *dflag;
    int b = blockIdx.x;
    int d = threadIdx.x;
    int ws_ = wstart[b], we_ = wend[b];
    float sl = 0.f, sr = 0.f, sg = 0.f;
    for (int c = 0; c < 8; ++c) {
        size_t base = ((size_t)(b * 8 + c)) * 3 * cD;
        sl += part[base + d];
        sr += part[base + cD + d];
        sg += part[base + 2 * cD + d];
    }
    left[b * cD + d]  = sl / fmaxf((float)ws_, 1.f);
    right[b * cD + d] = sr / fmaxf((float)(cL - we_), 1.f);
    glob[b * cD + d]  = sg / (float)cL;
    int ml = mlen[b];
    float sm = 0.f;
    for (int j = 0; j < cM; ++j) {
        if (j < ml) sm += ldx(emb, (size_t)mids[b * cM + j] * cD + d, f32);
    }
    motif[b * cD + d] = sm / fmaxf((float)ml, 1.f);
}

// ---------------------------------------------------------------------------
__global__ __launch_bounds__(512) void cond_temb_kernel(
    const float* __restrict__ motif, const float* __restrict__ left,
    const float* __restrict__ right, const float* __restrict__ glob,
    const void* __restrict__ t_arr,
    const void* __restrict__ cond_W, const void* __restrict__ cond_b,
    const void* __restrict__ tp_W, const void* __restrict__ tp_b,
    float* __restrict__ cond, float* __restrict__ temb,
    const int* __restrict__ dflag)
{
    const int f32 = *dflag;
    __shared__ float feat[4 * cD];
    __shared__ float tf[cD];
    int b = blockIdx.x;
    int d = threadIdx.x;
    feat[d]          = motif[b * cD + d];
    feat[cD + d]     = left[b * cD + d];
    feat[2 * cD + d] = right[b * cD + d];
    feat[3 * cD + d] = glob[b * cD + d];
    float t = ldx(t_arr, b, f32);
    const int half = cD / 2;
    {
        int j = d;
        if (j < half) {
            float fr = expf(-logf(10000.f) * (float)j / (float)(half - 1));
            tf[j] = sinf(t * fr);
        } else {
            float fr = expf(-logf(10000.f) * (float)(j - half) / (float)(half - 1));
            tf[j] = cosf(t * fr);
        }
    }
    __syncthreads();
    float sc = 0.f;
    for (int k = 0; k < 4 * cD; ++k)
        sc += feat[k] * ldx(cond_W, (size_t)d * (4 * cD) + k, f32);
    cond[b * cD + d] = sc + ldx(cond_b, d, f32);
    float st = 0.f;
    for (int k = 0; k < cD; ++k)
        st += tf[k] * ldx(tp_W, (size_t)d * cD + k, f32);
    temb[b * cD + d] = st + ldx(tp_b, d, f32);
}

// ---------------------------------------------------------------------------
__global__ __launch_bounds__(512) void build_x_kernel(
    const int* __restrict__ tok, const int* __restrict__ wstart,
    const int* __restrict__ wend, const void* __restrict__ t_arr,
    const void* __restrict__ x0, const void* __restrict__ emb,
    const float* __restrict__ cond, const float* __restrict__ temb,
    float* __restrict__ x, float* __restrict__ x1, float* __restrict__ xt,
    const int* __restrict__ dflag)
{
    const int f32 = *dflag;
    int row = blockIdx.x;
    int b = row / cS, s = row % cS;
    int d = threadIdx.x;
    if (s == 0) { x[(size_t)row * cD + d] = cond[b * cD + d]; return; }
    int i = s - 1;
    int ws_ = wstart[b], we_ = wend[b];
    int actual = min(max(we_ - ws_, 0), cWIN);
    int idx = min(ws_ + i, cL - 1);
    float x1v = 0.f;
    if (i < actual) x1v = ldx(emb, (size_t)tok[b * cL + idx] * cD + d, f32);
    float t = ldx(t_arr, b, f32);
    float x0v = ldx(x0, ((size_t)b * cWIN + i) * cD + d, f32);
    float xtv = (1.f - t) * x0v + t * x1v;
    size_t ro = ((size_t)b * cWIN + i) * cD + d;
    x1[ro] = x1v;
    xt[ro] = xtv;
    x[(size_t)row * cD + d] = xtv + temb[b * cD + d];
}

// ---------------------------------------------------------------------------
// Templated MFMA GEMM: C[M,N] = A[M,K] @ W[N,K]^T + bias (+relu).
// Block = 2x2 waves, each wave WM x WN via (WM/16)x(WN/16) mfma 16x16x32 bf16.
// A fp32 staged->bf16; W flagged dtype staged->bf16. LDS stride 40 (2-way free).
constexpr int GLDS = 40;
template<int BM, int BN, int WM, int WN>
__global__ __launch_bounds__(256) void gemm_mfma_t(
    const float* __restrict__ A, const void* __restrict__ Wb, size_t wOff,
    const void* __restrict__ biasb, size_t bOff, float* __restrict__ C,
    int Mdim, int Ndim, int Kdim, int relu, const int* __restrict__ dflag)
{
    constexpr int IM = WM / 16, IN = WN / 16;
    const int f32 = *dflag;
    const float* Wf = (const float*)Wb + wOff;
    const bf16*  Wh = (const bf16*)Wb + wOff;
    __shared__ unsigned short As[BM * GLDS];
    __shared__ unsigned short Bs[BN * GLDS];
    const int tid = threadIdx.x;
    const int lane = tid & 63;
    const int wid = tid >> 6;
    const int wm = wid >> 1, wn = wid & 1;
    const int quad = lane >> 4, lm = lane & 15;
    const int m0 = blockIdx.y * BM;
    const int n0 = blockIdx.x * BN;

    f32x4 acc[IM][IN];
    #pragma unroll
    for (int i = 0; i < IM; ++i)
        #pragma unroll
        for (int j = 0; j < IN; ++j)
            acc[i][j] = (f32x4){0.f, 0.f, 0.f, 0.f};

    for (int k0 = 0; k0 < Kdim; k0 += 32) {
        for (int chunk = tid; chunk < BM * 8; chunk += 256) {
            int row = chunk >> 3;
            int kc = (chunk & 7) * 4;
            int gr = m0 + row;
            float4 v = {0.f, 0.f, 0.f, 0.f};
            if (gr < Mdim)
                v = *(const float4*)(A + (size_t)gr * Kdim + k0 + kc);
            int o = row * GLDS + kc;
            As[o]     = f2bf(v.x);
            As[o + 1] = f2bf(v.y);
            As[o + 2] = f2bf(v.z);
            As[o + 3] = f2bf(v.w);
        }
        for (int chunk = tid; chunk < BN * 8; chunk += 256) {
            int row = chunk >> 3;
            int kc = (chunk & 7) * 4;
            size_t gro = (size_t)(n0 + row) * Kdim + k0 + kc;
            int o = row * GLDS + kc;
            if (f32) {
                float4 v = *(const float4*)(Wf + gro);
                Bs[o]     = f2bf(v.x);
                Bs[o + 1] = f2bf(v.y);
                Bs[o + 2] = f2bf(v.z);
                Bs[o + 3] = f2bf(v.w);
            } else {
                Bs[o]     = f2bf(b2f(Wh[gro]));
                Bs[o + 1] = f2bf(b2f(Wh[gro + 1]));
                Bs[o + 2] = f2bf(b2f(Wh[gro + 2]));
                Bs[o + 3] = f2bf(b2f(Wh[gro + 3]));
            }
        }
        __syncthreads();
        bf16x8 af[IM], bfr[IN];
        #pragma unroll
        for (int im = 0; im < IM; ++im) {
            int row = wm * WM + im * 16 + lm;
            af[im] = *(const bf16x8*)(As + row * GLDS + quad * 8);
        }
        #pragma unroll
        for (int in = 0; in < IN; ++in) {
            int row = wn * WN + in * 16 + lm;
            bfr[in] = *(const bf16x8*)(Bs + row * GLDS + quad * 8);
        }
        #pragma unroll
        for (int im = 0; im < IM; ++im)
            #pragma unroll
            for (int in = 0; in < IN; ++in)
                acc[im][in] = __builtin_amdgcn_mfma_f32_16x16x32_bf16(
                    af[im], bfr[in], acc[im][in], 0, 0, 0);
        __syncthreads();
    }

    #pragma unroll
    for (int in = 0; in < IN; ++in) {
        int gc = n0 + wn * WN + in * 16 + lm;
        float bv = ldx(biasb, bOff + gc, f32);
        #pragma unroll
        for (int im = 0; im < IM; ++im) {
            #pragma unroll
            for (int r = 0; r < 4; ++r) {
                int gr = m0 + wm * WM + im * 16 + quad * 4 + r;
                if (gr < Mdim) {
                    float v = acc[im][in][r] + bv;
                    if (relu) v = fmaxf(v, 0.f);
                    C[(size_t)gr * Ndim + gc] = v;
                }
            }
        }
    }
}

// ---------------------------------------------------------------------------
__global__ __launch_bounds__(128) void attn_kernel(
    const float* __restrict__ qkv, float* __restrict__ ctx)
{
    int s = blockIdx.x, h = blockIdx.y, b = blockIdx.z;
    __shared__ float qv[cHD];
    __shared__ float sc[cS];
    __shared__ float red[128];
    int tid = threadIdx.x;
    const float* base = qkv + (size_t)b * cS * (3 * cD);
    if (tid < cHD) qv[tid] = base[(size_t)s * (3 * cD) + h * cHD + tid];
    __syncthreads();
    for (int k = tid; k < cS; k += 128) {
        const float* kv = base + (size_t)k * (3 * cD) + cD + h * cHD;
        float dot = 0.f;
        #pragma unroll
        for (int e = 0; e < cHD; ++e) dot += qv[e] * kv[e];
        sc[k] = dot * 0.125f;
    }
    __syncthreads();
    float m = -1e30f;
    for (int k = tid; k < cS; k += 128) m = fmaxf(m, sc[k]);
    red[tid] = m; __syncthreads();
    for (int off = 64; off > 0; off >>= 1) {
        if (tid < off) red[tid] = fmaxf(red[tid], red[tid + off]);
        __syncthreads();
    }
    m = red[0];
    __syncthreads();
    float sum = 0.f;
    for (int k = tid; k < cS; k += 128) {
        float e = expf(sc[k] - m);
        sc[k] = e;
        sum += e;
    }
    red[tid] = sum; __syncthreads();
    for (int off = 64; off > 0; off >>= 1) {
        if (tid < off) red[tid] += red[tid + off];
        __syncthreads();
    }
    float inv = 1.f / red[0];
    if (tid < cHD) {
        float acc = 0.f;
        for (int k = 0; k < cS; ++k)
            acc += sc[k] * base[(size_t)k * (3 * cD) + 2 * cD + h * cHD + tid];
        ctx[((size_t)(b * cS + s)) * cD + h * cHD + tid] = acc * inv;
    }
}

// ---------------------------------------------------------------------------
__global__ __launch_bounds__(256) void resid_ln_kernel(
    float* __restrict__ x, const float* __restrict__ h,
    const void* __restrict__ g, const void* __restrict__ bta, size_t off,
    const int* __restrict__ dflag)
{
    const int f32 = *dflag;
    int row = blockIdx.x;
    int tid = threadIdx.x;
    __shared__ float red[256];
    float v[2];
    float s = 0.f;
    #pragma unroll
    for (int j = 0; j < 2; ++j) {
        int d = tid + j * 256;
        v[j] = x[(size_t)row * cD + d] + h[(size_t)row * cD + d];
        s += v[j];
    }
    red[tid] = s; __syncthreads();
    for (int o = 128; o > 0; o >>= 1) {
        if (tid < o) red[tid] += red[tid + o];
        __syncthreads();
    }
    float mean = red[0] / (float)cD;
    __syncthreads();
    float vs = 0.f;
    #pragma unroll
    for (int j = 0; j < 2; ++j) { float dd = v[j] - mean; vs += dd * dd; }
    red[tid] = vs; __syncthreads();
    for (int o = 128; o > 0; o >>= 1) {
        if (tid < o) red[tid] += red[tid + o];
        __syncthreads();
    }
    float rs = rsqrtf(red[0] / (float)cD + cEPS);
    #pragma unroll
    for (int j = 0; j < 2; ++j) {
        int d = tid + j * 256;
        x[(size_t)row * cD + d] = (v[j] - mean) * rs * ldx(g, off + d, f32)
                                  + ldx(bta, off + d, f32);
    }
}

// ---------------------------------------------------------------------------
__global__ __launch_bounds__(512) void copy_xs_kernel(
    const float* __restrict__ x, float* __restrict__ xs)
{
    int row = blockIdx.x;
    int b = row / cWIN, i = row % cWIN;
    int d = threadIdx.x;
    xs[(size_t)row * cD + d] = x[((size_t)(b * cS + 1 + i)) * cD + d];
}

// ---------------------------------------------------------------------------
__global__ __launch_bounds__(256) void vel_kernel(
    const float* __restrict__ pv, const float* __restrict__ x1,
    const void* __restrict__ x0, const int* __restrict__ wstart,
    const int* __restrict__ wend, float* __restrict__ velpart,
    const int* __restrict__ dflag)
{
    const int f32 = *dflag;
    int row = blockIdx.x;
    int b = row / cWIN, i = row % cWIN;
    int tid = threadIdx.x;
    int actual = min(max(wend[b] - wstart[b], 0), cWIN);
    if (i >= actual) {
        if (tid == 0) velpart[row] = 0.f;
        return;
    }
    __shared__ float red[256];
    float s = 0.f;
    for (int d = tid; d < cD; d += 256) {
        size_t o = (size_t)row * cD + d;
        float tv = x1[o] - ldx(x0, o, f32);
        float diff = pv[o] - tv;
        s += diff * diff;
    }
    red[tid] = s; __syncthreads();
    for (int off = 128; off > 0; off >>= 1) {
        if (tid < off) red[tid] += red[tid + off];
        __syncthreads();
    }
    if (tid == 0) velpart[row] = red[0];
}

// ---------------------------------------------------------------------------
__global__ __launch_bounds__(512) void predx1_kernel(
    const float* __restrict__ xt, const float* __restrict__ pv,
    const void* __restrict__ t_arr, float* __restrict__ outp,
    const int* __restrict__ dflag)
{
    const int f32 = *dflag;
    int row = blockIdx.x;
    int b = row / cWIN;
    int d = threadIdx.x;
    float t = ldx(t_arr, b, f32);
    size_t o = (size_t)row * cD + d;
    outp[o] = xt[o] + (1.f - t) * pv[o];
}

// ---------------------------------------------------------------------------
__global__ void labels_kernel(
    const int* __restrict__ tok, const int* __restrict__ wstart,
    const int* __restrict__ wend, int* __restrict__ labels)
{
    int r = blockIdx.x * 256 + threadIdx.x;
    if (r >= cB * cWIN) return;
    int b = r / cWIN, i = r % cWIN;
    int ws_ = wstart[b], we_ = wend[b];
    int actual = min(max(we_ - ws_, 0), cWIN);
    labels[r] = (i < actual) ? tok[b * cL + min(ws_ + i, cL - 1)] : -1;
}

// ---------------------------------------------------------------------------
// decode as MFMA GEMM + fused partial log-sum-exp.
// 128x128 tile, BK=32, 4 waves (2x2), wave 64x64 = 4x4 mfma 16x16x32 bf16.
// Rows M=2048, N=32000: both exact multiples -> no guards.
// Per-row reduce: lane-local over IN, then LDS [128][33], 32 cols per row.
// Label capture: fully-unrolled constant-index compares (no scratch demotion).
__global__ __launch_bounds__(256) void decode_mfma_kernel(
    const float* __restrict__ H, const void* __restrict__ dW,
    const void* __restrict__ db, const int* __restrict__ labels,
    float* __restrict__ pm, float* __restrict__ ps, float* __restrict__ lab,
    const int* __restrict__ dflag)
{
    const int f32 = *dflag;
    const float* Wf = (const float*)dW;
    const bf16*  Wh = (const bf16*)dW;
    __shared__ unsigned short As[128 * GLDS];
    __shared__ unsigned short Bs[128 * GLDS];
    const int tid = threadIdx.x;
    const int lane = tid & 63;
    const int wid = tid >> 6;
    const int wm = wid >> 1, wn = wid & 1;
    const int quad = lane >> 4, lm = lane & 15;
    const int nt = blockIdx.x;           // 0..249
    const int mt = blockIdx.y;           // 0..15
    const int m0 = mt * 128, n0 = nt * 128;

    f32x4 acc[4][4];
    #pragma unroll
    for (int i = 0; i < 4; ++i)
        #pragma unroll
        for (int j = 0; j < 4; ++j)
            acc[i][j] = (f32x4){0.f, 0.f, 0.f, 0.f};

    for (int k0 = 0; k0 < cD; k0 += 32) {
        #pragma unroll
        for (int t = 0; t < 4; ++t) {
            int chunk = tid + t * 256;
            int row = chunk >> 3;
            int kc = (chunk & 7) * 4;
            float4 v = *(const float4*)(H + (size_t)(m0 + row) * cD + k0 + kc);
            int o = row * GLDS + kc;
            As[o]     = f2bf(v.x);
            As[o + 1] = f2bf(v.y);
            As[o + 2] = f2bf(v.z);
            As[o + 3] = f2bf(v.w);
        }
        #pragma unroll
        for (int t = 0; t < 4; ++t) {
            int chunk = tid + t * 256;
            int row = chunk >> 3;
            int kc = (chunk & 7) * 4;
            size_t gro = (size_t)(n0 + row) * cD + k0 + kc;
            int o = row * GLDS + kc;
            if (f32) {
                float4 v = *(const float4*)(Wf + gro);
                Bs[o]     = f2bf(v.x);
                Bs[o + 1] = f2bf(v.y);
                Bs[o + 2] = f2bf(v.z);
                Bs[o + 3] = f2bf(v.w);
            } else {
                Bs[o]     = f2bf(b2f(Wh[gro]));
                Bs[o + 1] = f2bf(b2f(Wh[gro + 1]));
                Bs[o + 2] = f2bf(b2f(Wh[gro + 2]));
                Bs[o + 3] = f2bf(b2f(Wh[gro + 3]));
            }
        }
        __syncthreads();
        bf16x8 af[4], bfr[4];
        #pragma unroll
        for (int im = 0; im < 4; ++im) {
            int row = wm * 64 + im * 16 + lm;
            af[im] = *(const bf16x8*)(As + row * GLDS + quad * 8);
        }
        #pragma unroll
        for (int in = 0; in < 4; ++in) {
            int row = wn * 64 + in * 16 + lm;
            bfr[in] = *(const bf16x8*)(Bs + row * GLDS + quad * 8);
        }
        #pragma unroll
        for (int im = 0; im < 4; ++im)
            #pragma unroll
            for (int in = 0; in < 4; ++in)
                acc[im][in] = __builtin_amdgcn_mfma_f32_16x16x32_bf16(
                    af[im], bfr[in], acc[im][in], 0, 0, 0);
        __syncthreads();
    }

    // bias: col depends only on in (and lane)
    float bv[4];
    #pragma unroll
    for (int in = 0; in < 4; ++in)
        bv[in] = ldx(db, n0 + wn * 64 + in * 16 + lm, f32);
    #pragma unroll
    for (int im = 0; im < 4; ++im)
        #pragma unroll
        for (int in = 0; in < 4; ++in)
            #pragma unroll
            for (int r = 0; r < 4; ++r)
                acc[im][in][r] += bv[in];

    // label capture (constant indices; unique lane per (row,label) in this block)
    #pragma unroll
    for (int im = 0; im < 4; ++im) {
        #pragma unroll
        for (int r = 0; r < 4; ++r) {
            int gr = m0 + wm * 64 + im * 16 + quad * 4 + r;
            int lb = labels[gr];
            #pragma unroll
            for (int in = 0; in < 4; ++in) {
                int col = n0 + wn * 64 + in * 16 + lm;
                if (lb == col) lab[gr] = acc[im][in][r];
            }
        }
    }

    // per-row tile max: lane-local over in, then 32 cols per row in LDS
    __shared__ float red[128][33];
    __shared__ float mrow[128];
    #pragma unroll
    for (int im = 0; im < 4; ++im) {
        #pragma unroll
        for (int r = 0; r < 4; ++r) {
            int rl = wm * 64 + im * 16 + quad * 4 + r;
            float mx = acc[im][0][r];
            #pragma unroll
            for (int in = 1; in < 4; ++in) mx = fmaxf(mx, acc[im][in][r]);
            red[rl][wn * 16 + lm] = mx;
        }
    }
    __syncthreads();
    if (tid < 128) {
        float mx = red[tid][0];
        #pragma unroll
        for (int t = 1; t < 32; ++t) mx = fmaxf(mx, red[tid][t]);
        mrow[tid] = mx;
    }
    __syncthreads();
    // per-row tile sumexp
    #pragma unroll
    for (int im = 0; im < 4; ++im) {
        #pragma unroll
        for (int r = 0; r < 4; ++r) {
            int rl = wm * 64 + im * 16 + quad * 4 + r;
            float m_ = mrow[rl];
            float s = 0.f;
            #pragma unroll
            for (int in = 0; in < 4; ++in) s += expf(acc[im][in][r] - m_);
            red[rl][wn * 16 + lm] = s;
        }
    }
    __syncthreads();
    if (tid < 128) {
        float s = red[tid][0];
        #pragma unroll
        for (int t = 1; t < 32; ++t) s += red[tid][t];
        int gr = m0 + tid;
        pm[(size_t)gr * cNVT + nt] = mrow[tid];
        ps[(size_t)gr * cNVT + nt] = s;
    }
}

// ---------------------------------------------------------------------------
__global__ __launch_bounds__(64) void lse_reduce_kernel(
    const float* __restrict__ pm, const float* __restrict__ ps,
    const float* __restrict__ lab, const int* __restrict__ labels,
    float* __restrict__ logppart)
{
    int r = blockIdx.x;
    int tid = threadIdx.x;
    if (labels[r] < 0) {
        if (tid == 0) logppart[r] = 0.f;
        return;
    }
    float m = -1e30f;
    for (int c = tid; c < cNVT; c += 64) m = fmaxf(m, pm[(size_t)r * cNVT + c]);
    for (int off = 32; off > 0; off >>= 1) m = fmaxf(m, __shfl_down(m, off));
    m = __shfl(m, 0);
    float s = 0.f;
    for (int c = tid; c < cNVT; c += 64)
        s += ps[(size_t)r * cNVT + c] * expf(pm[(size_t)r * cNVT + c] - m);
    for (int off = 32; off > 0; off >>= 1) s += __shfl_down(s, off);
    if (tid == 0) logppart[r] = lab[r] - (m + logf(s));
}

// ---------------------------------------------------------------------------
__global__ __launch_bounds__(256) void finalize_kernel(
    const float* __restrict__ velpart, const float* __restrict__ logppart,
    const int* __restrict__ wstart, const int* __restrict__ wend,
    void* __restrict__ out, const int* __restrict__ dflag)
{
    const int f32 = *dflag;
    __shared__ float r1[256], r2[256];
    int tid = threadIdx.x;
    float s1 = 0.f, s2 = 0.f;
    for (int r = tid; r < cB * cWIN; r += 256) {
        s1 += velpart[r];
        s2 += logppart[r];
    }
    r1[tid] = s1; r2[tid] = s2; __syncthreads();
    for (int off = 128; off > 0; off >>= 1) {
        if (tid < off) { r1[tid] += r1[tid + off]; r2[tid] += r2[tid + off]; }
        __syncthreads();
    }
    if (tid == 0) {
        float cnt = 0.f;
        for (int b = 0; b < cB; ++b)
            cnt += (float)min(max(wend[b] - wstart[b], 0), cWIN);
        cnt = fmaxf(cnt, 1.f);
        float vel = r1[0] / (cnt * (float)cD);
        float recon = -r2[0] / cnt;
        float loss = vel + cRECON_W * recon;
        if (f32) ((float*)out)[0] = loss;
        else     ((bf16*)out)[0] = __float2bfloat16(loss);
    }
}

// ===========================================================================
extern "C" void kernel_launch(void* const* d_in, const int* in_sizes, int n_in,
                              void* d_out, int out_size, void* d_ws, size_t ws_size,
                              hipStream_t stream) {
    const int*  token_ids    = (const int*)d_in[0];
    const int*  motif_ids    = (const int*)d_in[1];
    const int*  motif_len    = (const int*)d_in[2];
    const int*  window_start = (const int*)d_in[3];
    const int*  window_end   = (const int*)d_in[4];
    const void* t_arr        = d_in[5];
    const void* x0           = d_in[6];
    const void* embed_table  = d_in[7];
    const void* decode_W     = d_in[8];
    const void* decode_b     = d_in[9];
    const void* adapter_W    = d_in[10];
    const void* adapter_b    = d_in[11];
    const void* time_proj_W  = d_in[12];
    const void* time_proj_b  = d_in[13];
    const void* cond_proj_W  = d_in[14];
    const void* cond_proj_b  = d_in[15];
    const void* qkv_W        = d_in[16];
    const void* qkv_b        = d_in[17];
    const void* attn_out_W   = d_in[18];
    const void* attn_out_b   = d_in[19];
    const void* ff1_W        = d_in[20];
    const void* ff1_b        = d_in[21];
    const void* ff2_W        = d_in[22];
    const void* ff2_b        = d_in[23];
    const void* ln1_g        = d_in[24];
    const void* ln1_b        = d_in[25];
    const void* ln2_g        = d_in[26];
    const void* ln2_b        = d_in[27];
    const void* out_W        = d_in[28];
    const void* out_b        = d_in[29];

    float* w = (float*)d_ws;
    const size_t SZ_X   = (size_t)cB * cS * cD;
    const size_t SZ_BA  = (size_t)cB * cS * cFF;
    const size_t SZ_ROW = (size_t)cB * cWIN * cD;
    float* x     = w;
    float* bufA  = x + SZ_X;
    float* bufB  = bufA + SZ_BA;
    float* bufC  = bufB + SZ_X;
    float* x1b   = bufC + SZ_X;
    float* xtb   = x1b + SZ_ROW;
    float* pvb   = xtb + SZ_ROW;
    float* h2b   = pvb + SZ_ROW;
    float* motif = h2b + SZ_ROW;
    float* left  = motif + (size_t)cB * cD;
    float* right = left + (size_t)cB * cD;
    float* glob  = right + (size_t)cB * cD;
    float* cond  = glob + (size_t)cB * cD;
    float* temb  = cond + (size_t)cB * cD;
    float* velpart = temb + (size_t)cB * cD;
    float* logppart = velpart + (size_t)cB * cWIN;
    int*   dflag = (int*)(logppart + (size_t)cB * cWIN);

    const int Wrows = cB * cWIN;                      // 2048
    float* pm  = bufA;                                // decode partials in bufA
    float* ps  = pm + (size_t)Wrows * cNVT;
    float* lab = ps + (size_t)Wrows * cNVT;
    int*   labels = (int*)(lab + Wrows);
    float* poolspart = bufC;                          // pools partials in bufC

    const int Mrows = cB * cS;                        // 2064

    detect_kernel<<<1, 256, 0, stream>>>(x0, dflag);
    pools_part_kernel<<<dim3(8, cB), cD, 0, stream>>>(token_ids, window_start,
        window_end, embed_table, poolspart, dflag);
    pools_combine_kernel<<<cB, cD, 0, stream>>>(poolspart, motif_ids, motif_len,
        window_start, window_end, embed_table, left, right, glob, motif, dflag);
    cond_temb_kernel<<<cB, cD, 0, stream>>>(motif, left, right, glob, t_arr,
        cond_proj_W, cond_proj_b, time_proj_W, time_proj_b, cond, temb, dflag);
    build_x_kernel<<<Mrows, cD, 0, stream>>>(token_ids, window_start, window_end,
        t_arr, x0, embed_table, cond, temb, x, x1b, xtb, dflag);

    // big tiles for N >= 1024; small tiles (4x the blocks) for N == 512
    auto gemm_big = [&](const float* A, const void* W, size_t wOff,
                        const void* bias, size_t bOff, float* C,
                        int M_, int N_, int K_, int relu) {
        dim3 grid(N_ / 128, (M_ + 127) / 128);
        gemm_mfma_t<128, 128, 64, 64><<<grid, 256, 0, stream>>>(
            A, W, wOff, bias, bOff, C, M_, N_, K_, relu, dflag);
    };
    auto gemm_small = [&](const float* A, const void* W, size_t wOff,
                          const void* bias, size_t bOff, float* C,
                          int M_, int N_, int K_, int relu) {
        dim3 grid(N_ / 64, (M_ + 63) / 64);
        gemm_mfma_t<64, 64, 32, 32><<<grid, 256, 0, stream>>>(
            A, W, wOff, bias, bOff, C, M_, N_, K_, relu, dflag);
    };

    for (int i = 0; i < cNL; ++i) {
        gemm_big(x, qkv_W, (size_t)i * 3 * cD * cD, qkv_b, (size_t)i * 3 * cD,
             bufA, Mrows, 3 * cD, cD, 0);
        attn_kernel<<<dim3(cS, cH, cB), 128, 0, stream>>>(bufA, bufB);
        gemm_small(bufB, attn_out_W, (size_t)i * cD * cD, attn_out_b, (size_t)i * cD,
             bufC, Mrows, cD, cD, 0);
        resid_ln_kernel<<<Mrows, 256, 0, stream>>>(x, bufC, ln1_g, ln1_b,
             (size_t)i * cD, dflag);
        gemm_big(x, ff1_W, (size_t)i * cFF * cD, ff1_b, (size_t)i * cFF,
             bufA, Mrows, cFF, cD, 1);
        gemm_small(bufA, ff2_W, (size_t)i * cD * cFF, ff2_b, (size_t)i * cD,
             bufC, Mrows, cD, cFF, 0);
        resid_ln_kernel<<<Mrows, 256, 0, stream>>>(x, bufC, ln2_g, ln2_b,
             (size_t)i * cD, dflag);
    }

    copy_xs_kernel<<<Wrows, cD, 0, stream>>>(x, bufC);
    gemm_small(bufC, out_W, 0, out_b, 0, pvb, Wrows, cD, cD, 0);
    vel_kernel<<<Wrows, 256, 0, stream>>>(pvb, x1b, x0, window_start, window_end,
        velpart, dflag);
    predx1_kernel<<<Wrows, cD, 0, stream>>>(xtb, pvb, t_arr, bufC, dflag);
    gemm_small(bufC, adapter_W, 0, adapter_b, 0, h2b, Wrows, cD, cD, 0);

    labels_kernel<<<(Wrows + 255) / 256, 256, 0, stream>>>(
        token_ids, window_start, window_end, labels);
    decode_mfma_kernel<<<dim3(cNVT, Wrows / 128), 256, 0, stream>>>(
        h2b, decode_W, decode_b, labels, pm, ps, lab, dflag);
    lse_reduce_kernel<<<Wrows, 64, 0, stream>>>(pm, ps, lab, labels, logppart);

    finalize_kernel<<<1, 256, 0, stream>>>(velpart, logppart,
        window_start, window_end, d_out, dflag);
}

// Round 8
// 2121.901 us; speedup vs baseline: 15.4871x; 1.2174x over previous
//
#include <hip/hip_runtime.h>
#include <hip/hip_bf16.h>
#include <math.h>

typedef __hip_bfloat16 bf16;

// Problem constants
constexpr int cB = 16, cL = 2048, cWIN = 128, cD = 512, cH = 8, cFF = 2048;
constexpr int cNL = 3, cV = 32000, cM = 32;
constexpr int cHD = cD / cH;     // 64
constexpr int cS = cWIN + 1;     // 129
constexpr float cEPS = 1e-5f;
constexpr float cRECON_W = 0.1f;
constexpr int cNVT = cV / 128;   // 250 vocab tiles

__device__ __forceinline__ float b2f(bf16 x) { return __bfloat162float(x); }

// dtype-agnostic load with ELEMENT offset: f32 flag selects interpretation.
__device__ __forceinline__ float ldx(const void* p, size_t i, int f32) {
    return f32 ? ((const float*)p)[i]
               : __bfloat162float(((const bf16*)p)[i]);
}

// f32 -> bf16 bits, round-to-nearest-even
__device__ __forceinline__ unsigned short f2bf(float f) {
    union { float f; unsigned int u; } v; v.f = f;
    unsigned int u = v.u + 0x7FFFu + ((v.u >> 16) & 1u);
    return (unsigned short)(u >> 16);
}

// MFMA fragment types
typedef short bf16x8 __attribute__((ext_vector_type(8)));
typedef float f32x4  __attribute__((ext_vector_type(4)));

// ---------------------------------------------------------------------------
__global__ void detect_kernel(const void* __restrict__ x0raw, int* __restrict__ flag)
{
    const unsigned short* h = (const unsigned short*)x0raw;
    int tid = threadIdx.x;
    int cnt = 0;
    for (int j = tid; j < 8192; j += 256) {
        unsigned short u = h[2 * j];
        int e = (u >> 7) & 0xFF;
        if (e >= 134) cnt++;
    }
    __shared__ int red[256];
    red[tid] = cnt; __syncthreads();
    for (int off = 128; off > 0; off >>= 1) {
        if (tid < off) red[tid] += red[tid + off];
        __syncthreads();
    }
    if (tid == 0) *flag = (red[0] > 400) ? 1 : 0;
}

// ---------------------------------------------------------------------------
__global__ __launch_bounds__(512) void pools_part_kernel(
    const int* __restrict__ tok, const int* __restrict__ wstart,
    const int* __restrict__ wend, const void* __restrict__ emb,
    float* __restrict__ part, const int* __restrict__ dflag)
{
    const int f32 = *dflag;
    int chunk = blockIdx.x;          // 0..7
    int b = blockIdx.y;              // 0..15
    int d = threadIdx.x;             // 0..511
    int ws_ = wstart[b], we_ = wend[b];
    float sl = 0.f, sr = 0.f, sg = 0.f;
    int l0 = chunk * 256;
    for (int l = l0; l < l0 + 256; ++l) {
        int t = tok[b * cL + l];
        float h = ldx(emb, (size_t)t * cD + d, f32);
        sg += h;
        if (l < ws_) sl += h;
        if (l >= we_) sr += h;
    }
    size_t base = ((size_t)(b * 8 + chunk)) * 3 * cD;
    part[base + d]            = sl;
    part[base + cD + d]       = sr;
    part[base + 2 * cD + d]   = sg;
}

// combine partials directly into contiguous feat[b][2048] = motif|left|right|glob
__global__ __launch_bounds__(512) void pools_combine_kernel(
    const float* __restrict__ part, const int* __restrict__ mids,
    const int* __restrict__ mlen, const int* __restrict__ wstart,
    const int* __restrict__ wend, const void* __restrict__ emb,
    float* __restrict__ feat, const int* __restrict__ dflag)
{
    const int f32 = *dflag;
    int b = blockIdx.x;
    int d = threadIdx.x;
    int ws_ = wstart[b], we_ = wend[b];
    float sl = 0.f, sr = 0.f, sg = 0.f;
    for (int c = 0; c < 8; ++c) {
        size_t base = ((size_t)(b * 8 + c)) * 3 * cD;
        sl += part[base + d];
        sr += part[base + cD + d];
        sg += part[base + 2 * cD + d];
    }
    int ml = mlen[b];
    float sm = 0.f;
    for (int j = 0; j < cM; ++j) {
        if (j < ml) sm += ldx(emb, (size_t)mids[b * cM + j] * cD + d, f32);
    }
    float* fr = feat + (size_t)b * (4 * cD);
    fr[d]            = sm / fmaxf((float)ml, 1.f);            // motif
    fr[cD + d]       = sl / fmaxf((float)ws_, 1.f);           // left
    fr[2 * cD + d]   = sr / fmaxf((float)(cL - we_), 1.f);    // right
    fr[3 * cD + d]   = sg / (float)cL;                        // glob
}

// ---------------------------------------------------------------------------
// time features tf[b][512] = [sin(t*freqs), cos(t*freqs)]
__global__ __launch_bounds__(512) void tf_kernel(
    const void* __restrict__ t_arr, float* __restrict__ tfb,
    const int* __restrict__ dflag)
{
    const int f32 = *dflag;
    int b = blockIdx.x;
    int j = threadIdx.x;
    float t = ldx(t_arr, b, f32);
    const int half = cD / 2;
    float v;
    if (j < half) {
        float fr = expf(-logf(10000.f) * (float)j / (float)(half - 1));
        v = sinf(t * fr);
    } else {
        float fr = expf(-logf(10000.f) * (float)(j - half) / (float)(half - 1));
        v = cosf(t * fr);
    }
    tfb[(size_t)b * cD + j] = v;
}

// ---------------------------------------------------------------------------
__global__ __launch_bounds__(512) void build_x_kernel(
    const int* __restrict__ tok, const int* __restrict__ wstart,
    const int* __restrict__ wend, const void* __restrict__ t_arr,
    const void* __restrict__ x0, const void* __restrict__ emb,
    const float* __restrict__ cond, const float* __restrict__ temb,
    float* __restrict__ x, float* __restrict__ x1, float* __restrict__ xt,
    const int* __restrict__ dflag)
{
    const int f32 = *dflag;
    int row = blockIdx.x;
    int b = row / cS, s = row % cS;
    int d = threadIdx.x;
    if (s == 0) { x[(size_t)row * cD + d] = cond[b * cD + d]; return; }
    int i = s - 1;
    int ws_ = wstart[b], we_ = wend[b];
    int actual = min(max(we_ - ws_, 0), cWIN);
    int idx = min(ws_ + i, cL - 1);
    float x1v = 0.f;
    if (i < actual) x1v = ldx(emb, (size_t)tok[b * cL + idx] * cD + d, f32);
    float t = ldx(t_arr, b, f32);
    float x0v = ldx(x0, ((size_t)b * cWIN + i) * cD + d, f32);
    float xtv = (1.f - t) * x0v + t * x1v;
    size_t ro = ((size_t)b * cWIN + i) * cD + d;
    x1[ro] = x1v;
    xt[ro] = xtv;
    x[(size_t)row * cD + d] = xtv + temb[b * cD + d];
}

// ---------------------------------------------------------------------------
// Templated MFMA GEMM: C[M,N] = A[M,K] @ W[N,K]^T + bias (+relu).
constexpr int GLDS = 40;
template<int BM, int BN, int WM, int WN>
__global__ __launch_bounds__(256) void gemm_mfma_t(
    const float* __restrict__ A, const void* __restrict__ Wb, size_t wOff,
    const void* __restrict__ biasb, size_t bOff, float* __restrict__ C,
    int Mdim, int Ndim, int Kdim, int relu, const int* __restrict__ dflag)
{
    constexpr int IM = WM / 16, IN = WN / 16;
    const int f32 = *dflag;
    const float* Wf = (const float*)Wb + wOff;
    const bf16*  Wh = (const bf16*)Wb + wOff;
    __shared__ unsigned short As[BM * GLDS];
    __shared__ unsigned short Bs[BN * GLDS];
    const int tid = threadIdx.x;
    const int lane = tid & 63;
    const int wid = tid >> 6;
    const int wm = wid >> 1, wn = wid & 1;
    const int quad = lane >> 4, lm = lane & 15;
    const int m0 = blockIdx.y * BM;
    const int n0 = blockIdx.x * BN;

    f32x4 acc[IM][IN];
    #pragma unroll
    for (int i = 0; i < IM; ++i)
        #pragma unroll
        for (int j = 0; j < IN; ++j)
            acc[i][j] = (f32x4){0.f, 0.f, 0.f, 0.f};

    for (int k0 = 0; k0 < Kdim; k0 += 32) {
        for (int chunk = tid; chunk < BM * 8; chunk += 256) {
            int row = chunk >> 3;
            int kc = (chunk & 7) * 4;
            int gr = m0 + row;
            float4 v = {0.f, 0.f, 0.f, 0.f};
            if (gr < Mdim)
                v = *(const float4*)(A + (size_t)gr * Kdim + k0 + kc);
            int o = row * GLDS + kc;
            As[o]     = f2bf(v.x);
            As[o + 1] = f2bf(v.y);
            As[o + 2] = f2bf(v.z);
            As[o + 3] = f2bf(v.w);
        }
        for (int chunk = tid; chunk < BN * 8; chunk += 256) {
            int row = chunk >> 3;
            int kc = (chunk & 7) * 4;
            size_t gro = (size_t)(n0 + row) * Kdim + k0 + kc;
            int o = row * GLDS + kc;
            if (f32) {
                float4 v = *(const float4*)(Wf + gro);
                Bs[o]     = f2bf(v.x);
                Bs[o + 1] = f2bf(v.y);
                Bs[o + 2] = f2bf(v.z);
                Bs[o + 3] = f2bf(v.w);
            } else {
                Bs[o]     = f2bf(b2f(Wh[gro]));
                Bs[o + 1] = f2bf(b2f(Wh[gro + 1]));
                Bs[o + 2] = f2bf(b2f(Wh[gro + 2]));
                Bs[o + 3] = f2bf(b2f(Wh[gro + 3]));
            }
        }
        __syncthreads();
        bf16x8 af[IM], bfr[IN];
        #pragma unroll
        for (int im = 0; im < IM; ++im) {
            int row = wm * WM + im * 16 + lm;
            af[im] = *(const bf16x8*)(As + row * GLDS + quad * 8);
        }
        #pragma unroll
        for (int in = 0; in < IN; ++in) {
            int row = wn * WN + in * 16 + lm;
            bfr[in] = *(const bf16x8*)(Bs + row * GLDS + quad * 8);
        }
        #pragma unroll
        for (int im = 0; im < IM; ++im)
            #pragma unroll
            for (int in = 0; in < IN; ++in)
                acc[im][in] = __builtin_amdgcn_mfma_f32_16x16x32_bf16(
                    af[im], bfr[in], acc[im][in], 0, 0, 0);
        __syncthreads();
    }

    #pragma unroll
    for (int in = 0; in < IN; ++in) {
        int gc = n0 + wn * WN + in * 16 + lm;
        float bv = ldx(biasb, bOff + gc, f32);
        #pragma unroll
        for (int im = 0; im < IM; ++im) {
            #pragma unroll
            for (int r = 0; r < 4; ++r) {
                int gr = m0 + wm * WM + im * 16 + quad * 4 + r;
                if (gr < Mdim) {
                    float v = acc[im][in][r] + bv;
                    if (relu) v = fmaxf(v, 0.f);
                    C[(size_t)gr * Ndim + gc] = v;
                }
            }
        }
    }
}

// ---------------------------------------------------------------------------
__global__ __launch_bounds__(128) void attn_kernel(
    const float* __restrict__ qkv, float* __restrict__ ctx)
{
    int s = blockIdx.x, h = blockIdx.y, b = blockIdx.z;
    __shared__ float qv[cHD];
    __shared__ float sc[cS];
    __shared__ float red[128];
    int tid = threadIdx.x;
    const float* base = qkv + (size_t)b * cS * (3 * cD);
    if (tid < cHD) qv[tid] = base[(size_t)s * (3 * cD) + h * cHD + tid];
    __syncthreads();
    for (int k = tid; k < cS; k += 128) {
        const float* kv = base + (size_t)k * (3 * cD) + cD + h * cHD;
        float dot = 0.f;
        #pragma unroll
        for (int e = 0; e < cHD; ++e) dot += qv[e] * kv[e];
        sc[k] = dot * 0.125f;
    }
    __syncthreads();
    float m = -1e30f;
    for (int k = tid; k < cS; k += 128) m = fmaxf(m, sc[k]);
    red[tid] = m; __syncthreads();
    for (int off = 64; off > 0; off >>= 1) {
        if (tid < off) red[tid] = fmaxf(red[tid], red[tid + off]);
        __syncthreads();
    }
    m = red[0];
    __syncthreads();
    float sum = 0.f;
    for (int k = tid; k < cS; k += 128) {
        float e = expf(sc[k] - m);
        sc[k] = e;
        sum += e;
    }
    red[tid] = sum; __syncthreads();
    for (int off = 64; off > 0; off >>= 1) {
        if (tid < off) red[tid] += red[tid + off];
        __syncthreads();
    }
    float inv = 1.f / red[0];
    if (tid < cHD) {
        float acc = 0.f;
        for (int k = 0; k < cS; ++k)
            acc += sc[k] * base[(size_t)k * (3 * cD) + 2 * cD + h * cHD + tid];
        ctx[((size_t)(b * cS + s)) * cD + h * cHD + tid] = acc * inv;
    }
}

// ---------------------------------------------------------------------------
__global__ __launch_bounds__(256) void resid_ln_kernel(
    float* __restrict__ x, const float* __restrict__ h,
    const void* __restrict__ g, const void* __restrict__ bta, size_t off,
    const int* __restrict__ dflag)
{
    const int f32 = *dflag;
    int row = blockIdx.x;
    int tid = threadIdx.x;
    __shared__ float red[256];
    float v[2];
    float s = 0.f;
    #pragma unroll
    for (int j = 0; j < 2; ++j) {
        int d = tid + j * 256;
        v[j] = x[(size_t)row * cD + d] + h[(size_t)row * cD + d];
        s += v[j];
    }
    red[tid] = s; __syncthreads();
    for (int o = 128; o > 0; o >>= 1) {
        if (tid < o) red[tid] += red[tid + o];
        __syncthreads();
    }
    float mean = red[0] / (float)cD;
    __syncthreads();
    float vs = 0.f;
    #pragma unroll
    for (int j = 0; j < 2; ++j) { float dd = v[j] - mean; vs += dd * dd; }
    red[tid] = vs; __syncthreads();
    for (int o = 128; o > 0; o >>= 1) {
        if (tid < o) red[tid] += red[tid + o];
        __syncthreads();
    }
    float rs = rsqrtf(red[0] / (float)cD + cEPS);
    #pragma unroll
    for (int j = 0; j < 2; ++j) {
        int d = tid + j * 256;
        x[(size_t)row * cD + d] = (v[j] - mean) * rs * ldx(g, off + d, f32)
                                  + ldx(bta, off + d, f32);
    }
}

// ---------------------------------------------------------------------------
__global__ __launch_bounds__(512) void copy_xs_kernel(
    const float* __restrict__ x, float* __restrict__ xs)
{
    int row = blockIdx.x;
    int b = row / cWIN, i = row % cWIN;
    int d = threadIdx.x;
    xs[(size_t)row * cD + d] = x[((size_t)(b * cS + 1 + i)) * cD + d];
}

// ---------------------------------------------------------------------------
__global__ __launch_bounds__(256) void vel_kernel(
    const float* __restrict__ pv, const float* __restrict__ x1,
    const void* __restrict__ x0, const int* __restrict__ wstart,
    const int* __restrict__ wend, float* __restrict__ velpart,
    const int* __restrict__ dflag)
{
    const int f32 = *dflag;
    int row = blockIdx.x;
    int b = row / cWIN, i = row % cWIN;
    int tid = threadIdx.x;
    int actual = min(max(wend[b] - wstart[b], 0), cWIN);
    if (i >= actual) {
        if (tid == 0) velpart[row] = 0.f;
        return;
    }
    __shared__ float red[256];
    float s = 0.f;
    for (int d = tid; d < cD; d += 256) {
        size_t o = (size_t)row * cD + d;
        float tv = x1[o] - ldx(x0, o, f32);
        float diff = pv[o] - tv;
        s += diff * diff;
    }
    red[tid] = s; __syncthreads();
    for (int off = 128; off > 0; off >>= 1) {
        if (tid < off) red[tid] += red[tid + off];
        __syncthreads();
    }
    if (tid == 0) velpart[row] = red[0];
}

// ---------------------------------------------------------------------------
__global__ __launch_bounds__(512) void predx1_kernel(
    const float* __restrict__ xt, const float* __restrict__ pv,
    const void* __restrict__ t_arr, float* __restrict__ outp,
    const int* __restrict__ dflag)
{
    const int f32 = *dflag;
    int row = blockIdx.x;
    int b = row / cWIN;
    int d = threadIdx.x;
    float t = ldx(t_arr, b, f32);
    size_t o = (size_t)row * cD + d;
    outp[o] = xt[o] + (1.f - t) * pv[o];
}

// ---------------------------------------------------------------------------
__global__ void labels_kernel(
    const int* __restrict__ tok, const int* __restrict__ wstart,
    const int* __restrict__ wend, int* __restrict__ labels)
{
    int r = blockIdx.x * 256 + threadIdx.x;
    if (r >= cB * cWIN) return;
    int b = r / cWIN, i = r % cWIN;
    int ws_ = wstart[b], we_ = wend[b];
    int actual = min(max(we_ - ws_, 0), cWIN);
    labels[r] = (i < actual) ? tok[b * cL + min(ws_ + i, cL - 1)] : -1;
}

// ---------------------------------------------------------------------------
// decode as MFMA GEMM + fused partial log-sum-exp (proven R7).
__global__ __launch_bounds__(256) void decode_mfma_kernel(
    const float* __restrict__ H, const void* __restrict__ dW,
    const void* __restrict__ db, const int* __restrict__ labels,
    float* __restrict__ pm, float* __restrict__ ps, float* __restrict__ lab,
    const int* __restrict__ dflag)
{
    const int f32 = *dflag;
    const float* Wf = (const float*)dW;
    const bf16*  Wh = (const bf16*)dW;
    __shared__ unsigned short As[128 * GLDS];
    __shared__ unsigned short Bs[128 * GLDS];
    const int tid = threadIdx.x;
    const int lane = tid & 63;
    const int wid = tid >> 6;
    const int wm = wid >> 1, wn = wid & 1;
    const int quad = lane >> 4, lm = lane & 15;
    const int nt = blockIdx.x;           // 0..249
    const int mt = blockIdx.y;           // 0..15
    const int m0 = mt * 128, n0 = nt * 128;

    f32x4 acc[4][4];
    #pragma unroll
    for (int i = 0; i < 4; ++i)
        #pragma unroll
        for (int j = 0; j < 4; ++j)
            acc[i][j] = (f32x4){0.f, 0.f, 0.f, 0.f};

    for (int k0 = 0; k0 < cD; k0 += 32) {
        #pragma unroll
        for (int t = 0; t < 4; ++t) {
            int chunk = tid + t * 256;
            int row = chunk >> 3;
            int kc = (chunk & 7) * 4;
            float4 v = *(const float4*)(H + (size_t)(m0 + row) * cD + k0 + kc);
            int o = row * GLDS + kc;
            As[o]     = f2bf(v.x);
            As[o + 1] = f2bf(v.y);
            As[o + 2] = f2bf(v.z);
            As[o + 3] = f2bf(v.w);
        }
        #pragma unroll
        for (int t = 0; t < 4; ++t) {
            int chunk = tid + t * 256;
            int row = chunk >> 3;
            int kc = (chunk & 7) * 4;
            size_t gro = (size_t)(n0 + row) * cD + k0 + kc;
            int o = row * GLDS + kc;
            if (f32) {
                float4 v = *(const float4*)(Wf + gro);
                Bs[o]     = f2bf(v.x);
                Bs[o + 1] = f2bf(v.y);
                Bs[o + 2] = f2bf(v.z);
                Bs[o + 3] = f2bf(v.w);
            } else {
                Bs[o]     = f2bf(b2f(Wh[gro]));
                Bs[o + 1] = f2bf(b2f(Wh[gro + 1]));
                Bs[o + 2] = f2bf(b2f(Wh[gro + 2]));
                Bs[o + 3] = f2bf(b2f(Wh[gro + 3]));
            }
        }
        __syncthreads();
        bf16x8 af[4], bfr[4];
        #pragma unroll
        for (int im = 0; im < 4; ++im) {
            int row = wm * 64 + im * 16 + lm;
            af[im] = *(const bf16x8*)(As + row * GLDS + quad * 8);
        }
        #pragma unroll
        for (int in = 0; in < 4; ++in) {
            int row = wn * 64 + in * 16 + lm;
            bfr[in] = *(const bf16x8*)(Bs + row * GLDS + quad * 8);
        }
        #pragma unroll
        for (int im = 0; im < 4; ++im)
            #pragma unroll
            for (int in = 0; in < 4; ++in)
                acc[im][in] = __builtin_amdgcn_mfma_f32_16x16x32_bf16(
                    af[im], bfr[in], acc[im][in], 0, 0, 0);
        __syncthreads();
    }

    float bv[4];
    #pragma unroll
    for (int in = 0; in < 4; ++in)
        bv[in] = ldx(db, n0 + wn * 64 + in * 16 + lm, f32);
    #pragma unroll
    for (int im = 0; im < 4; ++im)
        #pragma unroll
        for (int in = 0; in < 4; ++in)
            #pragma unroll
            for (int r = 0; r < 4; ++r)
                acc[im][in][r] += bv[in];

    #pragma unroll
    for (int im = 0; im < 4; ++im) {
        #pragma unroll
        for (int r = 0; r < 4; ++r) {
            int gr = m0 + wm * 64 + im * 16 + quad * 4 + r;
            int lb = labels[gr];
            #pragma unroll
            for (int in = 0; in < 4; ++in) {
                int col = n0 + wn * 64 + in * 16 + lm;
                if (lb == col) lab[gr] = acc[im][in][r];
            }
        }
    }

    __shared__ float red[128][33];
    __shared__ float mrow[128];
    #pragma unroll
    for (int im = 0; im < 4; ++im) {
        #pragma unroll
        for (int r = 0; r < 4; ++r) {
            int rl = wm * 64 + im * 16 + quad * 4 + r;
            float mx = acc[im][0][r];
            #pragma unroll
            for (int in = 1; in < 4; ++in) mx = fmaxf(mx, acc[im][in][r]);
            red[rl][wn * 16 + lm] = mx;
        }
    }
    __syncthreads();
    if (tid < 128) {
        float mx = red[tid][0];
        #pragma unroll
        for (int t = 1; t < 32; ++t) mx = fmaxf(mx, red[tid][t]);
        mrow[tid] = mx;
    }
    __syncthreads();
    #pragma unroll
    for (int im = 0; im < 4; ++im) {
        #pragma unroll
        for (int r = 0; r < 4; ++r) {
            int rl = wm * 64 + im * 16 + quad * 4 + r;
            float m_ = mrow[rl];
            float s = 0.f;
            #pragma unroll
            for (int in = 0; in < 4; ++in) s += expf(acc[im][in][r] - m_);
            red[rl][wn * 16 + lm] = s;
        }
    }
    __syncthreads();
    if (tid < 128) {
        float s = red[tid][0];
        #pragma unroll
        for (int t = 1; t < 32; ++t) s += red[tid][t];
        int gr = m0 + tid;
        pm[(size_t)gr * cNVT + nt] = mrow[tid];
        ps[(size_t)gr * cNVT + nt] = s;
    }
}

// ---------------------------------------------------------------------------
__global__ __launch_bounds__(64) void lse_reduce_kernel(
    const float* __restrict__ pm, const float* __restrict__ ps,
    const float* __restrict__ lab, const int* __restrict__ labels,
    float* __restrict__ logppart)
{
    int r = blockIdx.x;
    int tid = threadIdx.x;
    if (labels[r] < 0) {
        if (tid == 0) logppart[r] = 0.f;
        return;
    }
    float m = -1e30f;
    for (int c = tid; c < cNVT; c += 64) m = fmaxf(m, pm[(size_t)r * cNVT + c]);
    for (int off = 32; off > 0; off >>= 1) m = fmaxf(m, __shfl_down(m, off));
    m = __shfl(m, 0);
    float s = 0.f;
    for (int c = tid; c < cNVT; c += 64)
        s += ps[(size_t)r * cNVT + c] * expf(pm[(size_t)r * cNVT + c] - m);
    for (int off = 32; off > 0; off >>= 1) s += __shfl_down(s, off);
    if (tid == 0) logppart[r] = lab[r] - (m + logf(s));
}

// ---------------------------------------------------------------------------
__global__ __launch_bounds__(256) void finalize_kernel(
    const float* __restrict__ velpart, const float* __restrict__ logppart,
    const int* __restrict__ wstart, const int* __restrict__ wend,
    void* __restrict__ out, const int* __restrict__ dflag)
{
    const int f32 = *dflag;
    __shared__ float r1[256], r2[256];
    int tid = threadIdx.x;
    float s1 = 0.f, s2 = 0.f;
    for (int r = tid; r < cB * cWIN; r += 256) {
        s1 += velpart[r];
        s2 += logppart[r];
    }
    r1[tid] = s1; r2[tid] = s2; __syncthreads();
    for (int off = 128; off > 0; off >>= 1) {
        if (tid < off) { r1[tid] += r1[tid + off]; r2[tid] += r2[tid + off]; }
        __syncthreads();
    }
    if (tid == 0) {
        float cnt = 0.f;
        for (int b = 0; b < cB; ++b)
            cnt += (float)min(max(wend[b] - wstart[b], 0), cWIN);
        cnt = fmaxf(cnt, 1.f);
        float vel = r1[0] / (cnt * (float)cD);
        float recon = -r2[0] / cnt;
        float loss = vel + cRECON_W * recon;
        if (f32) ((float*)out)[0] = loss;
        else     ((bf16*)out)[0] = __float2bfloat16(loss);
    }
}

// ===========================================================================
extern "C" void kernel_launch(void* const* d_in, const int* in_sizes, int n_in,
                              void* d_out, int out_size, void* d_ws, size_t ws_size,
                              hipStream_t stream) {
    const int*  token_ids    = (const int*)d_in[0];
    const int*  motif_ids    = (const int*)d_in[1];
    const int*  motif_len    = (const int*)d_in[2];
    const int*  window_start = (const int*)d_in[3];
    const int*  window_end   = (const int*)d_in[4];
    const void* t_arr        = d_in[5];
    const void* x0           = d_in[6];
    const void* embed_table  = d_in[7];
    const void* decode_W     = d_in[8];
    const void* decode_b     = d_in[9];
    const void* adapter_W    = d_in[10];
    const void* adapter_b    = d_in[11];
    const void* time_proj_W  = d_in[12];
    const void* time_proj_b  = d_in[13];
    const void* cond_proj_W  = d_in[14];
    const void* cond_proj_b  = d_in[15];
    const void* qkv_W        = d_in[16];
    const void* qkv_b        = d_in[17];
    const void* attn_out_W   = d_in[18];
    const void* attn_out_b   = d_in[19];
    const void* ff1_W        = d_in[20];
    const void* ff1_b        = d_in[21];
    const void* ff2_W        = d_in[22];
    const void* ff2_b        = d_in[23];
    const void* ln1_g        = d_in[24];
    const void* ln1_b        = d_in[25];
    const void* ln2_g        = d_in[26];
    const void* ln2_b        = d_in[27];
    const void* out_W        = d_in[28];
    const void* out_b        = d_in[29];

    float* w = (float*)d_ws;
    const size_t SZ_X   = (size_t)cB * cS * cD;
    const size_t SZ_BA  = (size_t)cB * cS * cFF;
    const size_t SZ_ROW = (size_t)cB * cWIN * cD;
    float* x     = w;
    float* bufA  = x + SZ_X;
    float* bufB  = bufA + SZ_BA;
    float* bufC  = bufB + SZ_X;
    float* x1b   = bufC + SZ_X;
    float* xtb   = x1b + SZ_ROW;
    float* pvb   = xtb + SZ_ROW;
    float* h2b   = pvb + SZ_ROW;
    float* feat  = h2b + SZ_ROW;                      // [B, 4D] = motif|left|right|glob
    float* tfb   = feat + (size_t)cB * 4 * cD;        // [B, D] time features
    float* cond  = tfb + (size_t)cB * cD;             // [B, D]
    float* temb  = cond + (size_t)cB * cD;            // [B, D]
    float* velpart = temb + (size_t)cB * cD;
    float* logppart = velpart + (size_t)cB * cWIN;
    int*   dflag = (int*)(logppart + (size_t)cB * cWIN);

    const int Wrows = cB * cWIN;                      // 2048
    float* pm  = bufA;                                // decode partials in bufA
    float* ps  = pm + (size_t)Wrows * cNVT;
    float* lab = ps + (size_t)Wrows * cNVT;
    int*   labels = (int*)(lab + Wrows);
    float* poolspart = bufC;                          // pools partials in bufC

    const int Mrows = cB * cS;                        // 2064

    auto gemm_big = [&](const float* A, const void* W, size_t wOff,
                        const void* bias, size_t bOff, float* C,
                        int M_, int N_, int K_, int relu) {
        dim3 grid(N_ / 128, (M_ + 127) / 128);
        gemm_mfma_t<128, 128, 64, 64><<<grid, 256, 0, stream>>>(
            A, W, wOff, bias, bOff, C, M_, N_, K_, relu, dflag);
    };
    auto gemm_small = [&](const float* A, const void* W, size_t wOff,
                          const void* bias, size_t bOff, float* C,
                          int M_, int N_, int K_, int relu) {
        dim3 grid(N_ / 64, (M_ + 63) / 64);
        gemm_mfma_t<64, 64, 32, 32><<<grid, 256, 0, stream>>>(
            A, W, wOff, bias, bOff, C, M_, N_, K_, relu, dflag);
    };

    detect_kernel<<<1, 256, 0, stream>>>(x0, dflag);
    pools_part_kernel<<<dim3(8, cB), cD, 0, stream>>>(token_ids, window_start,
        window_end, embed_table, poolspart, dflag);
    pools_combine_kernel<<<cB, cD, 0, stream>>>(poolspart, motif_ids, motif_len,
        window_start, window_end, embed_table, feat, dflag);
    tf_kernel<<<cB, cD, 0, stream>>>(t_arr, tfb, dflag);
    // cond = feat @ cond_proj_W^T + b  (M=16, N=512, K=2048)
    gemm_small(feat, cond_proj_W, 0, cond_proj_b, 0, cond, cB, cD, 4 * cD, 0);
    // temb = tf @ time_proj_W^T + b    (M=16, N=512, K=512)
    gemm_small(tfb, time_proj_W, 0, time_proj_b, 0, temb, cB, cD, cD, 0);
    build_x_kernel<<<Mrows, cD, 0, stream>>>(token_ids, window_start, window_end,
        t_arr, x0, embed_table, cond, temb, x, x1b, xtb, dflag);

    for (int i = 0; i < cNL; ++i) {
        gemm_big(x, qkv_W, (size_t)i * 3 * cD * cD, qkv_b, (size_t)i * 3 * cD,
             bufA, Mrows, 3 * cD, cD, 0);
        attn_kernel<<<dim3(cS, cH, cB), 128, 0, stream>>>(bufA, bufB);
        gemm_small(bufB, attn_out_W, (size_t)i * cD * cD, attn_out_b, (size_t)i * cD,
             bufC, Mrows, cD, cD, 0);
        resid_ln_kernel<<<Mrows, 256, 0, stream>>>(x, bufC, ln1_g, ln1_b,
             (size_t)i * cD, dflag);
        gemm_big(x, ff1_W, (size_t)i * cFF * cD, ff1_b, (size_t)i * cFF,
             bufA, Mrows, cFF, cD, 1);
        gemm_small(bufA, ff2_W, (size_t)i * cD * cFF, ff2_b, (size_t)i * cD,
             bufC, Mrows, cD, cFF, 0);
        resid_ln_kernel<<<Mrows, 256, 0, stream>>>(x, bufC, ln2_g, ln2_b,
             (size_t)i * cD, dflag);
    }

    copy_xs_kernel<<<Wrows, cD, 0, stream>>>(x, bufC);
    gemm_small(bufC, out_W, 0, out_b, 0, pvb, Wrows, cD, cD, 0);
    vel_kernel<<<Wrows, 256, 0, stream>>>(pvb, x1b, x0, window_start, window_end,
        velpart, dflag);
    predx1_kernel<<<Wrows, cD, 0, stream>>>(xtb, pvb, t_arr, bufC, dflag);
    gemm_small(bufC, adapter_W, 0, adapter_b, 0, h2b, Wrows, cD, cD, 0);

    labels_kernel<<<(Wrows + 255) / 256, 256, 0, stream>>>(
        token_ids, window_start, window_end, labels);
    decode_mfma_kernel<<<dim3(cNVT, Wrows / 128), 256, 0, stream>>>(
        h2b, decode_W, decode_b, labels, pm, ps, lab, dflag);
    lse_reduce_kernel<<<Wrows, 64, 0, stream>>>(pm, ps, lab, labels, logppart);

    finalize_kernel<<<1, 256, 0, stream>>>(velpart, logppart,
        window_start, window_end, d_out, dflag);
}

// Round 9
// 1936.706 us; speedup vs baseline: 16.9680x; 1.0956x over previous
//
#include <hip/hip_runtime.h>
#include <hip/hip_bf16.h>
#include <math.h>

typedef __hip_bfloat16 bf16;

// Problem constants
constexpr int cB = 16, cL = 2048, cWIN = 128, cD = 512, cH = 8, cFF = 2048;
constexpr int cNL = 3, cV = 32000, cM = 32;
constexpr int cHD = cD / cH;     // 64
constexpr int cS = cWIN + 1;     // 129
constexpr float cEPS = 1e-5f;
constexpr float cRECON_W = 0.1f;
constexpr int cNVT = cV / 128;   // 250 vocab tiles

__device__ __forceinline__ float b2f(bf16 x) { return __bfloat162float(x); }

// dtype-agnostic load with ELEMENT offset: f32 flag selects interpretation.
__device__ __forceinline__ float ldx(const void* p, size_t i, int f32) {
    return f32 ? ((const float*)p)[i]
               : __bfloat162float(((const bf16*)p)[i]);
}

// f32 -> bf16 bits, round-to-nearest-even
__device__ __forceinline__ unsigned int f2bf(float f) {
    union { float f; unsigned int u; } v; v.f = f;
    unsigned int u = v.u + 0x7FFFu + ((v.u >> 16) & 1u);
    return u >> 16;
}

// MFMA fragment types
typedef short bf16x8 __attribute__((ext_vector_type(8)));
typedef float f32x4  __attribute__((ext_vector_type(4)));

// ---------------------------------------------------------------------------
__global__ void detect_kernel(const void* __restrict__ x0raw, int* __restrict__ flag)
{
    const unsigned short* h = (const unsigned short*)x0raw;
    int tid = threadIdx.x;
    int cnt = 0;
    for (int j = tid; j < 8192; j += 256) {
        unsigned short u = h[2 * j];
        int e = (u >> 7) & 0xFF;
        if (e >= 134) cnt++;
    }
    __shared__ int red[256];
    red[tid] = cnt; __syncthreads();
    for (int off = 128; off > 0; off >>= 1) {
        if (tid < off) red[tid] += red[tid + off];
        __syncthreads();
    }
    if (tid == 0) *flag = (red[0] > 400) ? 1 : 0;
}

// ---------------------------------------------------------------------------
__global__ __launch_bounds__(512) void pools_part_kernel(
    const int* __restrict__ tok, const int* __restrict__ wstart,
    const int* __restrict__ wend, const void* __restrict__ emb,
    float* __restrict__ part, const int* __restrict__ dflag)
{
    const int f32 = *dflag;
    int chunk = blockIdx.x;          // 0..7
    int b = blockIdx.y;              // 0..15
    int d = threadIdx.x;             // 0..511
    int ws_ = wstart[b], we_ = wend[b];
    float sl = 0.f, sr = 0.f, sg = 0.f;
    int l0 = chunk * 256;
    for (int l = l0; l < l0 + 256; ++l) {
        int t = tok[b * cL + l];
        float h = ldx(emb, (size_t)t * cD + d, f32);
        sg += h;
        if (l < ws_) sl += h;
        if (l >= we_) sr += h;
    }
    size_t base = ((size_t)(b * 8 + chunk)) * 3 * cD;
    part[base + d]            = sl;
    part[base + cD + d]       = sr;
    part[base + 2 * cD + d]   = sg;
}

// combine partials directly into contiguous feat[b][2048] = motif|left|right|glob
__global__ __launch_bounds__(512) void pools_combine_kernel(
    const float* __restrict__ part, const int* __restrict__ mids,
    const int* __restrict__ mlen, const int* __restrict__ wstart,
    const int* __restrict__ wend, const void* __restrict__ emb,
    float* __restrict__ feat, const int* __restrict__ dflag)
{
    const int f32 = *dflag;
    int b = blockIdx.x;
    int d = threadIdx.x;
    int ws_ = wstart[b], we_ = wend[b];
    float sl = 0.f, sr = 0.f, sg = 0.f;
    for (int c = 0; c < 8; ++c) {
        size_t base = ((size_t)(b * 8 + c)) * 3 * cD;
        sl += part[base + d];
        sr += part[base + cD + d];
        sg += part[base + 2 * cD + d];
    }
    int ml = mlen[b];
    float sm = 0.f;
    for (int j = 0; j < cM; ++j) {
        if (j < ml) sm += ldx(emb, (size_t)mids[b * cM + j] * cD + d, f32);
    }
    float* fr = feat + (size_t)b * (4 * cD);
    fr[d]            = sm / fmaxf((float)ml, 1.f);            // motif
    fr[cD + d]       = sl / fmaxf((float)ws_, 1.f);           // left
    fr[2 * cD + d]   = sr / fmaxf((float)(cL - we_), 1.f);    // right
    fr[3 * cD + d]   = sg / (float)cL;                        // glob
}

// ---------------------------------------------------------------------------
__global__ __launch_bounds__(512) void tf_kernel(
    const void* __restrict__ t_arr, float* __restrict__ tfb,
    const int* __restrict__ dflag)
{
    const int f32 = *dflag;
    int b = blockIdx.x;
    int j = threadIdx.x;
    float t = ldx(t_arr, b, f32);
    const int half = cD / 2;
    float v;
    if (j < half) {
        float fr = expf(-logf(10000.f) * (float)j / (float)(half - 1));
        v = sinf(t * fr);
    } else {
        float fr = expf(-logf(10000.f) * (float)(j - half) / (float)(half - 1));
        v = cosf(t * fr);
    }
    tfb[(size_t)b * cD + j] = v;
}

// ---------------------------------------------------------------------------
__global__ __launch_bounds__(512) void build_x_kernel(
    const int* __restrict__ tok, const int* __restrict__ wstart,
    const int* __restrict__ wend, const void* __restrict__ t_arr,
    const void* __restrict__ x0, const void* __restrict__ emb,
    const float* __restrict__ cond, const float* __restrict__ temb,
    float* __restrict__ x, float* __restrict__ x1, float* __restrict__ xt,
    const int* __restrict__ dflag)
{
    const int f32 = *dflag;
    int row = blockIdx.x;
    int b = row / cS, s = row % cS;
    int d = threadIdx.x;
    if (s == 0) { x[(size_t)row * cD + d] = cond[b * cD + d]; return; }
    int i = s - 1;
    int ws_ = wstart[b], we_ = wend[b];
    int actual = min(max(we_ - ws_, 0), cWIN);
    int idx = min(ws_ + i, cL - 1);
    float x1v = 0.f;
    if (i < actual) x1v = ldx(emb, (size_t)tok[b * cL + idx] * cD + d, f32);
    float t = ldx(t_arr, b, f32);
    float x0v = ldx(x0, ((size_t)b * cWIN + i) * cD + d, f32);
    float xtv = (1.f - t) * x0v + t * x1v;
    size_t ro = ((size_t)b * cWIN + i) * cD + d;
    x1[ro] = x1v;
    xt[ro] = xtv;
    x[(size_t)row * cD + d] = xtv + temb[b * cD + d];
}

// ---------------------------------------------------------------------------
// Templated MFMA GEMM with PACKED staging stores (R9).
constexpr int GLDS = 40;
template<int BM, int BN, int WM, int WN>
__global__ __launch_bounds__(256) void gemm_mfma_t(
    const float* __restrict__ A, const void* __restrict__ Wb, size_t wOff,
    const void* __restrict__ biasb, size_t bOff, float* __restrict__ C,
    int Mdim, int Ndim, int Kdim, int relu, const int* __restrict__ dflag)
{
    constexpr int IM = WM / 16, IN = WN / 16;
    const int f32 = *dflag;
    const float* Wf = (const float*)Wb + wOff;
    const bf16*  Wh = (const bf16*)Wb + wOff;
    __shared__ unsigned short As[BM * GLDS];
    __shared__ unsigned short Bs[BN * GLDS];
    const int tid = threadIdx.x;
    const int lane = tid & 63;
    const int wid = tid >> 6;
    const int wm = wid >> 1, wn = wid & 1;
    const int quad = lane >> 4, lm = lane & 15;
    const int m0 = blockIdx.y * BM;
    const int n0 = blockIdx.x * BN;

    f32x4 acc[IM][IN];
    #pragma unroll
    for (int i = 0; i < IM; ++i)
        #pragma unroll
        for (int j = 0; j < IN; ++j)
            acc[i][j] = (f32x4){0.f, 0.f, 0.f, 0.f};

    for (int k0 = 0; k0 < Kdim; k0 += 32) {
        for (int chunk = tid; chunk < BM * 8; chunk += 256) {
            int row = chunk >> 3;
            int kc = (chunk & 7) * 4;
            int gr = m0 + row;
            float4 v = {0.f, 0.f, 0.f, 0.f};
            if (gr < Mdim)
                v = *(const float4*)(A + (size_t)gr * Kdim + k0 + kc);
            unsigned int p0 = f2bf(v.x) | (f2bf(v.y) << 16);
            unsigned int p1 = f2bf(v.z) | (f2bf(v.w) << 16);
            *(uint2*)(As + row * GLDS + kc) = make_uint2(p0, p1);
        }
        for (int chunk = tid; chunk < BN * 8; chunk += 256) {
            int row = chunk >> 3;
            int kc = (chunk & 7) * 4;
            size_t gro = (size_t)(n0 + row) * Kdim + k0 + kc;
            if (f32) {
                float4 v = *(const float4*)(Wf + gro);
                unsigned int p0 = f2bf(v.x) | (f2bf(v.y) << 16);
                unsigned int p1 = f2bf(v.z) | (f2bf(v.w) << 16);
                *(uint2*)(Bs + row * GLDS + kc) = make_uint2(p0, p1);
            } else {
                *(uint2*)(Bs + row * GLDS + kc) = *(const uint2*)(Wh + gro);
            }
        }
        __syncthreads();
        bf16x8 af[IM], bfr[IN];
        #pragma unroll
        for (int im = 0; im < IM; ++im) {
            int row = wm * WM + im * 16 + lm;
            af[im] = *(const bf16x8*)(As + row * GLDS + quad * 8);
        }
        #pragma unroll
        for (int in = 0; in < IN; ++in) {
            int row = wn * WN + in * 16 + lm;
            bfr[in] = *(const bf16x8*)(Bs + row * GLDS + quad * 8);
        }
        #pragma unroll
        for (int im = 0; im < IM; ++im)
            #pragma unroll
            for (int in = 0; in < IN; ++in)
                acc[im][in] = __builtin_amdgcn_mfma_f32_16x16x32_bf16(
                    af[im], bfr[in], acc[im][in], 0, 0, 0);
        __syncthreads();
    }

    #pragma unroll
    for (int in = 0; in < IN; ++in) {
        int gc = n0 + wn * WN + in * 16 + lm;
        float bv = ldx(biasb, bOff + gc, f32);
        #pragma unroll
        for (int im = 0; im < IM; ++im) {
            #pragma unroll
            for (int r = 0; r < 4; ++r) {
                int gr = m0 + wm * WM + im * 16 + quad * 4 + r;
                if (gr < Mdim) {
                    float v = acc[im][in][r] + bv;
                    if (relu) v = fmaxf(v, 0.f);
                    C[(size_t)gr * Ndim + gc] = v;
                }
            }
        }
    }
}

// ---------------------------------------------------------------------------
__global__ __launch_bounds__(128) void attn_kernel(
    const float* __restrict__ qkv, float* __restrict__ ctx)
{
    int s = blockIdx.x, h = blockIdx.y, b = blockIdx.z;
    __shared__ float qv[cHD];
    __shared__ float sc[cS];
    __shared__ float red[128];
    int tid = threadIdx.x;
    const float* base = qkv + (size_t)b * cS * (3 * cD);
    if (tid < cHD) qv[tid] = base[(size_t)s * (3 * cD) + h * cHD + tid];
    __syncthreads();
    for (int k = tid; k < cS; k += 128) {
        const float* kv = base + (size_t)k * (3 * cD) + cD + h * cHD;
        float dot = 0.f;
        #pragma unroll
        for (int e = 0; e < cHD; ++e) dot += qv[e] * kv[e];
        sc[k] = dot * 0.125f;
    }
    __syncthreads();
    float m = -1e30f;
    for (int k = tid; k < cS; k += 128) m = fmaxf(m, sc[k]);
    red[tid] = m; __syncthreads();
    for (int off = 64; off > 0; off >>= 1) {
        if (tid < off) red[tid] = fmaxf(red[tid], red[tid + off]);
        __syncthreads();
    }
    m = red[0];
    __syncthreads();
    float sum = 0.f;
    for (int k = tid; k < cS; k += 128) {
        float e = expf(sc[k] - m);
        sc[k] = e;
        sum += e;
    }
    red[tid] = sum; __syncthreads();
    for (int off = 64; off > 0; off >>= 1) {
        if (tid < off) red[tid] += red[tid + off];
        __syncthreads();
    }
    float inv = 1.f / red[0];
    if (tid < cHD) {
        float acc = 0.f;
        for (int k = 0; k < cS; ++k)
            acc += sc[k] * base[(size_t)k * (3 * cD) + 2 * cD + h * cHD + tid];
        ctx[((size_t)(b * cS + s)) * cD + h * cHD + tid] = acc * inv;
    }
}

// ---------------------------------------------------------------------------
__global__ __launch_bounds__(256) void resid_ln_kernel(
    float* __restrict__ x, const float* __restrict__ h,
    const void* __restrict__ g, const void* __restrict__ bta, size_t off,
    const int* __restrict__ dflag)
{
    const int f32 = *dflag;
    int row = blockIdx.x;
    int tid = threadIdx.x;
    __shared__ float red[256];
    float v[2];
    float s = 0.f;
    #pragma unroll
    for (int j = 0; j < 2; ++j) {
        int d = tid + j * 256;
        v[j] = x[(size_t)row * cD + d] + h[(size_t)row * cD + d];
        s += v[j];
    }
    red[tid] = s; __syncthreads();
    for (int o = 128; o > 0; o >>= 1) {
        if (tid < o) red[tid] += red[tid + o];
        __syncthreads();
    }
    float mean = red[0] / (float)cD;
    __syncthreads();
    float vs = 0.f;
    #pragma unroll
    for (int j = 0; j < 2; ++j) { float dd = v[j] - mean; vs += dd * dd; }
    red[tid] = vs; __syncthreads();
    for (int o = 128; o > 0; o >>= 1) {
        if (tid < o) red[tid] += red[tid + o];
        __syncthreads();
    }
    float rs = rsqrtf(red[0] / (float)cD + cEPS);
    #pragma unroll
    for (int j = 0; j < 2; ++j) {
        int d = tid + j * 256;
        x[(size_t)row * cD + d] = (v[j] - mean) * rs * ldx(g, off + d, f32)
                                  + ldx(bta, off + d, f32);
    }
}

// ---------------------------------------------------------------------------
__global__ __launch_bounds__(512) void copy_xs_kernel(
    const float* __restrict__ x, float* __restrict__ xs)
{
    int row = blockIdx.x;
    int b = row / cWIN, i = row % cWIN;
    int d = threadIdx.x;
    xs[(size_t)row * cD + d] = x[((size_t)(b * cS + 1 + i)) * cD + d];
}

// ---------------------------------------------------------------------------
__global__ __launch_bounds__(256) void vel_kernel(
    const float* __restrict__ pv, const float* __restrict__ x1,
    const void* __restrict__ x0, const int* __restrict__ wstart,
    const int* __restrict__ wend, float* __restrict__ velpart,
    const int* __restrict__ dflag)
{
    const int f32 = *dflag;
    int row = blockIdx.x;
    int b = row / cWIN, i = row % cWIN;
    int tid = threadIdx.x;
    int actual = min(max(wend[b] - wstart[b], 0), cWIN);
    if (i >= actual) {
        if (tid == 0) velpart[row] = 0.f;
        return;
    }
    __shared__ float red[256];
    float s = 0.f;
    for (int d = tid; d < cD; d += 256) {
        size_t o = (size_t)row * cD + d;
        float tv = x1[o] - ldx(x0, o, f32);
        float diff = pv[o] - tv;
        s += diff * diff;
    }
    red[tid] = s; __syncthreads();
    for (int off = 128; off > 0; off >>= 1) {
        if (tid < off) red[tid] += red[tid + off];
        __syncthreads();
    }
    if (tid == 0) velpart[row] = red[0];
}

// ---------------------------------------------------------------------------
__global__ __launch_bounds__(512) void predx1_kernel(
    const float* __restrict__ xt, const float* __restrict__ pv,
    const void* __restrict__ t_arr, float* __restrict__ outp,
    const int* __restrict__ dflag)
{
    const int f32 = *dflag;
    int row = blockIdx.x;
    int b = row / cWIN;
    int d = threadIdx.x;
    float t = ldx(t_arr, b, f32);
    size_t o = (size_t)row * cD + d;
    outp[o] = xt[o] + (1.f - t) * pv[o];
}

// ---------------------------------------------------------------------------
__global__ void labels_kernel(
    const int* __restrict__ tok, const int* __restrict__ wstart,
    const int* __restrict__ wend, int* __restrict__ labels)
{
    int r = blockIdx.x * 256 + threadIdx.x;
    if (r >= cB * cWIN) return;
    int b = r / cWIN, i = r % cWIN;
    int ws_ = wstart[b], we_ = wend[b];
    int actual = min(max(we_ - ws_, 0), cWIN);
    labels[r] = (i < actual) ? tok[b * cL + min(ws_ + i, cL - 1)] : -1;
}

// ---------------------------------------------------------------------------
// pre-convert decode_W -> bf16 (only needed when input is f32)
__global__ __launch_bounds__(256) void cvt_w_kernel(
    const void* __restrict__ Wsrc, unsigned short* __restrict__ dst,
    const int* __restrict__ dflag)
{
    if (!*dflag) return;   // bf16 input: decode reads source directly
    const float4* src = (const float4*)Wsrc;
    size_t n4 = (size_t)cV * cD / 4;
    for (size_t i = (size_t)blockIdx.x * 256 + threadIdx.x; i < n4;
         i += (size_t)gridDim.x * 256) {
        float4 v = src[i];
        unsigned int p0 = f2bf(v.x) | (f2bf(v.y) << 16);
        unsigned int p1 = f2bf(v.z) | (f2bf(v.w) << 16);
        ((uint2*)dst)[i] = make_uint2(p0, p1);
    }
}

// pre-convert h2b (always f32 workspace) -> bf16
__global__ __launch_bounds__(256) void cvt_h_kernel(
    const float* __restrict__ src, unsigned short* __restrict__ dst)
{
    size_t i = (size_t)blockIdx.x * 256 + threadIdx.x;   // n4 = 262144
    float4 v = ((const float4*)src)[i];
    unsigned int p0 = f2bf(v.x) | (f2bf(v.y) << 16);
    unsigned int p1 = f2bf(v.z) | (f2bf(v.w) << 16);
    ((uint2*)dst)[i] = make_uint2(p0, p1);
}

// ---------------------------------------------------------------------------
// FAST decode: pre-converted bf16 A and W, XCD-aware swizzle.
// 1D grid 4096: xcd=bid&7 owns 32 contiguous vocab tiles (4MB bf16 = fits L2).
__global__ __launch_bounds__(256) void decode_mfma2_kernel(
    const unsigned short* __restrict__ hbf, const unsigned short* __restrict__ wbf,
    const void* __restrict__ dW, const void* __restrict__ db,
    const int* __restrict__ labels,
    float* __restrict__ pm, float* __restrict__ ps, float* __restrict__ lab,
    const int* __restrict__ dflag)
{
    const int f32 = *dflag;
    const unsigned short* Wsrc = f32 ? wbf : (const unsigned short*)dW;
    const int bid = blockIdx.x;
    const int xcd = bid & 7;
    const int local = bid >> 3;            // 0..511
    const int nt = xcd * 32 + (local >> 4);
    const int mt = local & 15;
    if (nt >= cNVT) return;                // uniform exit, no barriers crossed
    const int m0 = mt * 128, n0 = nt * 128;

    __shared__ unsigned short As[128 * GLDS];
    __shared__ unsigned short Bs[128 * GLDS];
    const int tid = threadIdx.x;
    const int lane = tid & 63;
    const int wid = tid >> 6;
    const int wm = wid >> 1, wn = wid & 1;
    const int quad = lane >> 4, lm = lane & 15;

    f32x4 acc[4][4];
    #pragma unroll
    for (int i = 0; i < 4; ++i)
        #pragma unroll
        for (int j = 0; j < 4; ++j)
            acc[i][j] = (f32x4){0.f, 0.f, 0.f, 0.f};

    for (int k0 = 0; k0 < cD; k0 += 32) {
        #pragma unroll
        for (int t = 0; t < 2; ++t) {
            int idx = tid + t * 256;       // 0..511
            int row = idx >> 2, c = idx & 3;
            uint4 v = *(const uint4*)(hbf + (size_t)(m0 + row) * cD + k0 + c * 8);
            *(uint4*)(As + row * GLDS + c * 8) = v;
        }
        #pragma unroll
        for (int t = 0; t < 2; ++t) {
            int idx = tid + t * 256;
            int row = idx >> 2, c = idx & 3;
            uint4 v = *(const uint4*)(Wsrc + (size_t)(n0 + row) * cD + k0 + c * 8);
            *(uint4*)(Bs + row * GLDS + c * 8) = v;
        }
        __syncthreads();
        bf16x8 af[4], bfr[4];
        #pragma unroll
        for (int im = 0; im < 4; ++im) {
            int row = wm * 64 + im * 16 + lm;
            af[im] = *(const bf16x8*)(As + row * GLDS + quad * 8);
        }
        #pragma unroll
        for (int in = 0; in < 4; ++in) {
            int row = wn * 64 + in * 16 + lm;
            bfr[in] = *(const bf16x8*)(Bs + row * GLDS + quad * 8);
        }
        #pragma unroll
        for (int im = 0; im < 4; ++im)
            #pragma unroll
            for (int in = 0; in < 4; ++in)
                acc[im][in] = __builtin_amdgcn_mfma_f32_16x16x32_bf16(
                    af[im], bfr[in], acc[im][in], 0, 0, 0);
        __syncthreads();
    }

    float bv[4];
    #pragma unroll
    for (int in = 0; in < 4; ++in)
        bv[in] = ldx(db, n0 + wn * 64 + in * 16 + lm, f32);
    #pragma unroll
    for (int im = 0; im < 4; ++im)
        #pragma unroll
        for (int in = 0; in < 4; ++in)
            #pragma unroll
            for (int r = 0; r < 4; ++r)
                acc[im][in][r] += bv[in];

    #pragma unroll
    for (int im = 0; im < 4; ++im) {
        #pragma unroll
        for (int r = 0; r < 4; ++r) {
            int gr = m0 + wm * 64 + im * 16 + quad * 4 + r;
            int lb = labels[gr];
            #pragma unroll
            for (int in = 0; in < 4; ++in) {
                int col = n0 + wn * 64 + in * 16 + lm;
                if (lb == col) lab[gr] = acc[im][in][r];
            }
        }
    }

    __shared__ float red[128][33];
    __shared__ float mrow[128];
    #pragma unroll
    for (int im = 0; im < 4; ++im) {
        #pragma unroll
        for (int r = 0; r < 4; ++r) {
            int rl = wm * 64 + im * 16 + quad * 4 + r;
            float mx = acc[im][0][r];
            #pragma unroll
            for (int in = 1; in < 4; ++in) mx = fmaxf(mx, acc[im][in][r]);
            red[rl][wn * 16 + lm] = mx;
        }
    }
    __syncthreads();
    if (tid < 128) {
        float mx = red[tid][0];
        #pragma unroll
        for (int t = 1; t < 32; ++t) mx = fmaxf(mx, red[tid][t]);
        mrow[tid] = mx;
    }
    __syncthreads();
    #pragma unroll
    for (int im = 0; im < 4; ++im) {
        #pragma unroll
        for (int r = 0; r < 4; ++r) {
            int rl = wm * 64 + im * 16 + quad * 4 + r;
            float m_ = mrow[rl];
            float s = 0.f;
            #pragma unroll
            for (int in = 0; in < 4; ++in) s += expf(acc[im][in][r] - m_);
            red[rl][wn * 16 + lm] = s;
        }
    }
    __syncthreads();
    if (tid < 128) {
        float s = red[tid][0];
        #pragma unroll
        for (int t = 1; t < 32; ++t) s += red[tid][t];
        int gr = m0 + tid;
        pm[(size_t)gr * cNVT + nt] = mrow[tid];
        ps[(size_t)gr * cNVT + nt] = s;
    }
}

// ---------------------------------------------------------------------------
// FALLBACK decode (proven R8): in-kernel conversion, (nt, mt) grid.
__global__ __launch_bounds__(256) void decode_mfma_kernel(
    const float* __restrict__ H, const void* __restrict__ dW,
    const void* __restrict__ db, const int* __restrict__ labels,
    float* __restrict__ pm, float* __restrict__ ps, float* __restrict__ lab,
    const int* __restrict__ dflag)
{
    const int f32 = *dflag;
    const float* Wf = (const float*)dW;
    const bf16*  Wh = (const bf16*)dW;
    __shared__ unsigned short As[128 * GLDS];
    __shared__ unsigned short Bs[128 * GLDS];
    const int tid = threadIdx.x;
    const int lane = tid & 63;
    const int wid = tid >> 6;
    const int wm = wid >> 1, wn = wid & 1;
    const int quad = lane >> 4, lm = lane & 15;
    const int nt = blockIdx.x;
    const int mt = blockIdx.y;
    const int m0 = mt * 128, n0 = nt * 128;

    f32x4 acc[4][4];
    #pragma unroll
    for (int i = 0; i < 4; ++i)
        #pragma unroll
        for (int j = 0; j < 4; ++j)
            acc[i][j] = (f32x4){0.f, 0.f, 0.f, 0.f};

    for (int k0 = 0; k0 < cD; k0 += 32) {
        #pragma unroll
        for (int t = 0; t < 4; ++t) {
            int chunk = tid + t * 256;
            int row = chunk >> 3;
            int kc = (chunk & 7) * 4;
            float4 v = *(const float4*)(H + (size_t)(m0 + row) * cD + k0 + kc);
            unsigned int p0 = f2bf(v.x) | (f2bf(v.y) << 16);
            unsigned int p1 = f2bf(v.z) | (f2bf(v.w) << 16);
            *(uint2*)(As + row * GLDS + kc) = make_uint2(p0, p1);
        }
        #pragma unroll
        for (int t = 0; t < 4; ++t) {
            int chunk = tid + t * 256;
            int row = chunk >> 3;
            int kc = (chunk & 7) * 4;
            size_t gro = (size_t)(n0 + row) * cD + k0 + kc;
            if (f32) {
                float4 v = *(const float4*)(Wf + gro);
                unsigned int p0 = f2bf(v.x) | (f2bf(v.y) << 16);
                unsigned int p1 = f2bf(v.z) | (f2bf(v.w) << 16);
                *(uint2*)(Bs + row * GLDS + kc) = make_uint2(p0, p1);
            } else {
                *(uint2*)(Bs + row * GLDS + kc) = *(const uint2*)(Wh + gro);
            }
        }
        __syncthreads();
        bf16x8 af[4], bfr[4];
        #pragma unroll
        for (int im = 0; im < 4; ++im) {
            int row = wm * 64 + im * 16 + lm;
            af[im] = *(const bf16x8*)(As + row * GLDS + quad * 8);
        }
        #pragma unroll
        for (int in = 0; in < 4; ++in) {
            int row = wn * 64 + in * 16 + lm;
            bfr[in] = *(const bf16x8*)(Bs + row * GLDS + quad * 8);
        }
        #pragma unroll
        for (int im = 0; im < 4; ++im)
            #pragma unroll
            for (int in = 0; in < 4; ++in)
                acc[im][in] = __builtin_amdgcn_mfma_f32_16x16x32_bf16(
                    af[im], bfr[in], acc[im][in], 0, 0, 0);
        __syncthreads();
    }

    float bv[4];
    #pragma unroll
    for (int in = 0; in < 4; ++in)
        bv[in] = ldx(db, n0 + wn * 64 + in * 16 + lm, f32);
    #pragma unroll
    for (int im = 0; im < 4; ++im)
        #pragma unroll
        for (int in = 0; in < 4; ++in)
            #pragma unroll
            for (int r = 0; r < 4; ++r)
                acc[im][in][r] += bv[in];

    #pragma unroll
    for (int im = 0; im < 4; ++im) {
        #pragma unroll
        for (int r = 0; r < 4; ++r) {
            int gr = m0 + wm * 64 + im * 16 + quad * 4 + r;
            int lb = labels[gr];
            #pragma unroll
            for (int in = 0; in < 4; ++in) {
                int col = n0 + wn * 64 + in * 16 + lm;
                if (lb == col) lab[gr] = acc[im][in][r];
            }
        }
    }

    __shared__ float red[128][33];
    __shared__ float mrow[128];
    #pragma unroll
    for (int im = 0; im < 4; ++im) {
        #pragma unroll
        for (int r = 0; r < 4; ++r) {
            int rl = wm * 64 + im * 16 + quad * 4 + r;
            float mx = acc[im][0][r];
            #pragma unroll
            for (int in = 1; in < 4; ++in) mx = fmaxf(mx, acc[im][in][r]);
            red[rl][wn * 16 + lm] = mx;
        }
    }
    __syncthreads();
    if (tid < 128) {
        float mx = red[tid][0];
        #pragma unroll
        for (int t = 1; t < 32; ++t) mx = fmaxf(mx, red[tid][t]);
        mrow[tid] = mx;
    }
    __syncthreads();
    #pragma unroll
    for (int im = 0; im < 4; ++im) {
        #pragma unroll
        for (int r = 0; r < 4; ++r) {
            int rl = wm * 64 + im * 16 + quad * 4 + r;
            float m_ = mrow[rl];
            float s = 0.f;
            #pragma unroll
            for (int in = 0; in < 4; ++in) s += expf(acc[im][in][r] - m_);
            red[rl][wn * 16 + lm] = s;
        }
    }
    __syncthreads();
    if (tid < 128) {
        float s = red[tid][0];
        #pragma unroll
        for (int t = 1; t < 32; ++t) s += red[tid][t];
        int gr = m0 + tid;
        pm[(size_t)gr * cNVT + nt] = mrow[tid];
        ps[(size_t)gr * cNVT + nt] = s;
    }
}

// ---------------------------------------------------------------------------
__global__ __launch_bounds__(64) void lse_reduce_kernel(
    const float* __restrict__ pm, const float* __restrict__ ps,
    const float* __restrict__ lab, const int* __restrict__ labels,
    float* __restrict__ logppart)
{
    int r = blockIdx.x;
    int tid = threadIdx.x;
    if (labels[r] < 0) {
        if (tid == 0) logppart[r] = 0.f;
        return;
    }
    float m = -1e30f;
    for (int c = tid; c < cNVT; c += 64) m = fmaxf(m, pm[(size_t)r * cNVT + c]);
    for (int off = 32; off > 0; off >>= 1) m = fmaxf(m, __shfl_down(m, off));
    m = __shfl(m, 0);
    float s = 0.f;
    for (int c = tid; c < cNVT; c += 64)
        s += ps[(size_t)r * cNVT + c] * expf(pm[(size_t)r * cNVT + c] - m);
    for (int off = 32; off > 0; off >>= 1) s += __shfl_down(s, off);
    if (tid == 0) logppart[r] = lab[r] - (m + logf(s));
}

// ---------------------------------------------------------------------------
__global__ __launch_bounds__(256) void finalize_kernel(
    const float* __restrict__ velpart, const float* __restrict__ logppart,
    const int* __restrict__ wstart, const int* __restrict__ wend,
    void* __restrict__ out, const int* __restrict__ dflag)
{
    const int f32 = *dflag;
    __shared__ float r1[256], r2[256];
    int tid = threadIdx.x;
    float s1 = 0.f, s2 = 0.f;
    for (int r = tid; r < cB * cWIN; r += 256) {
        s1 += velpart[r];
        s2 += logppart[r];
    }
    r1[tid] = s1; r2[tid] = s2; __syncthreads();
    for (int off = 128; off > 0; off >>= 1) {
        if (tid < off) { r1[tid] += r1[tid + off]; r2[tid] += r2[tid + off]; }
        __syncthreads();
    }
    if (tid == 0) {
        float cnt = 0.f;
        for (int b = 0; b < cB; ++b)
            cnt += (float)min(max(wend[b] - wstart[b], 0), cWIN);
        cnt = fmaxf(cnt, 1.f);
        float vel = r1[0] / (cnt * (float)cD);
        float recon = -r2[0] / cnt;
        float loss = vel + cRECON_W * recon;
        if (f32) ((float*)out)[0] = loss;
        else     ((bf16*)out)[0] = __float2bfloat16(loss);
    }
}

// ===========================================================================
extern "C" void kernel_launch(void* const* d_in, const int* in_sizes, int n_in,
                              void* d_out, int out_size, void* d_ws, size_t ws_size,
                              hipStream_t stream) {
    const int*  token_ids    = (const int*)d_in[0];
    const int*  motif_ids    = (const int*)d_in[1];
    const int*  motif_len    = (const int*)d_in[2];
    const int*  window_start = (const int*)d_in[3];
    const int*  window_end   = (const int*)d_in[4];
    const void* t_arr        = d_in[5];
    const void* x0           = d_in[6];
    const void* embed_table  = d_in[7];
    const void* decode_W     = d_in[8];
    const void* decode_b     = d_in[9];
    const void* adapter_W    = d_in[10];
    const void* adapter_b    = d_in[11];
    const void* time_proj_W  = d_in[12];
    const void* time_proj_b  = d_in[13];
    const void* cond_proj_W  = d_in[14];
    const void* cond_proj_b  = d_in[15];
    const void* qkv_W        = d_in[16];
    const void* qkv_b        = d_in[17];
    const void* attn_out_W   = d_in[18];
    const void* attn_out_b   = d_in[19];
    const void* ff1_W        = d_in[20];
    const void* ff1_b        = d_in[21];
    const void* ff2_W        = d_in[22];
    const void* ff2_b        = d_in[23];
    const void* ln1_g        = d_in[24];
    const void* ln1_b        = d_in[25];
    const void* ln2_g        = d_in[26];
    const void* ln2_b        = d_in[27];
    const void* out_W        = d_in[28];
    const void* out_b        = d_in[29];

    float* w = (float*)d_ws;
    const size_t SZ_X   = (size_t)cB * cS * cD;
    const size_t SZ_BA  = (size_t)cB * cS * cFF;
    const size_t SZ_ROW = (size_t)cB * cWIN * cD;
    float* x     = w;
    float* bufA  = x + SZ_X;
    float* bufB  = bufA + SZ_BA;
    float* bufC  = bufB + SZ_X;
    float* x1b   = bufC + SZ_X;
    float* xtb   = x1b + SZ_ROW;
    float* pvb   = xtb + SZ_ROW;
    float* h2b   = pvb + SZ_ROW;
    float* feat  = h2b + SZ_ROW;                      // [B, 4D]
    float* tfb   = feat + (size_t)cB * 4 * cD;        // [B, D]
    float* cond  = tfb + (size_t)cB * cD;
    float* temb  = cond + (size_t)cB * cD;
    float* velpart = temb + (size_t)cB * cD;
    float* logppart = velpart + (size_t)cB * cWIN;
    int*   dflag = (int*)(logppart + (size_t)cB * cWIN);
    float* wsend = (float*)(dflag + 16);              // end of base layout
    unsigned short* wbf = (unsigned short*)wsend;     // [cV*cD] bf16 W copy

    const size_t need_bytes = ((char*)wsend - (char*)d_ws)
                            + (size_t)cV * cD * sizeof(unsigned short) + 256;
    const bool fast_decode = ws_size >= need_bytes;

    const int Wrows = cB * cWIN;                      // 2048
    float* pm  = bufA;                                // decode partials in bufA
    float* ps  = pm + (size_t)Wrows * cNVT;
    float* lab = ps + (size_t)Wrows * cNVT;
    int*   labels = (int*)(lab + Wrows);
    float* poolspart = bufC;                          // pools partials in bufC
    unsigned short* hbf = (unsigned short*)bufC;      // bf16 H (bufC free at decode)

    const int Mrows = cB * cS;                        // 2064

    auto gemm_big = [&](const float* A, const void* W, size_t wOff,
                        const void* bias, size_t bOff, float* C,
                        int M_, int N_, int K_, int relu) {
        dim3 grid(N_ / 128, (M_ + 127) / 128);
        gemm_mfma_t<128, 128, 64, 64><<<grid, 256, 0, stream>>>(
            A, W, wOff, bias, bOff, C, M_, N_, K_, relu, dflag);
    };
    auto gemm_small = [&](const float* A, const void* W, size_t wOff,
                          const void* bias, size_t bOff, float* C,
                          int M_, int N_, int K_, int relu) {
        dim3 grid(N_ / 64, (M_ + 63) / 64);
        gemm_mfma_t<64, 64, 32, 32><<<grid, 256, 0, stream>>>(
            A, W, wOff, bias, bOff, C, M_, N_, K_, relu, dflag);
    };

    detect_kernel<<<1, 256, 0, stream>>>(x0, dflag);
    if (fast_decode)
        cvt_w_kernel<<<4096, 256, 0, stream>>>(decode_W, wbf, dflag);
    pools_part_kernel<<<dim3(8, cB), cD, 0, stream>>>(token_ids, window_start,
        window_end, embed_table, poolspart, dflag);
    pools_combine_kernel<<<cB, cD, 0, stream>>>(poolspart, motif_ids, motif_len,
        window_start, window_end, embed_table, feat, dflag);
    tf_kernel<<<cB, cD, 0, stream>>>(t_arr, tfb, dflag);
    gemm_small(feat, cond_proj_W, 0, cond_proj_b, 0, cond, cB, cD, 4 * cD, 0);
    gemm_small(tfb, time_proj_W, 0, time_proj_b, 0, temb, cB, cD, cD, 0);
    build_x_kernel<<<Mrows, cD, 0, stream>>>(token_ids, window_start, window_end,
        t_arr, x0, embed_table, cond, temb, x, x1b, xtb, dflag);

    for (int i = 0; i < cNL; ++i) {
        gemm_big(x, qkv_W, (size_t)i * 3 * cD * cD, qkv_b, (size_t)i * 3 * cD,
             bufA, Mrows, 3 * cD, cD, 0);
        attn_kernel<<<dim3(cS, cH, cB), 128, 0, stream>>>(bufA, bufB);
        gemm_small(bufB, attn_out_W, (size_t)i * cD * cD, attn_out_b, (size_t)i * cD,
             bufC, Mrows, cD, cD, 0);
        resid_ln_kernel<<<Mrows, 256, 0, stream>>>(x, bufC, ln1_g, ln1_b,
             (size_t)i * cD, dflag);
        gemm_big(x, ff1_W, (size_t)i * cFF * cD, ff1_b, (size_t)i * cFF,
             bufA, Mrows, cFF, cD, 1);
        gemm_small(bufA, ff2_W, (size_t)i * cD * cFF, ff2_b, (size_t)i * cD,
             bufC, Mrows, cD, cFF, 0);
        resid_ln_kernel<<<Mrows, 256, 0, stream>>>(x, bufC, ln2_g, ln2_b,
             (size_t)i * cD, dflag);
    }

    copy_xs_kernel<<<Wrows, cD, 0, stream>>>(x, bufC);
    gemm_small(bufC, out_W, 0, out_b, 0, pvb, Wrows, cD, cD, 0);
    vel_kernel<<<Wrows, 256, 0, stream>>>(pvb, x1b, x0, window_start, window_end,
        velpart, dflag);
    predx1_kernel<<<Wrows, cD, 0, stream>>>(xtb, pvb, t_arr, bufC, dflag);
    gemm_small(bufC, adapter_W, 0, adapter_b, 0, h2b, Wrows, cD, cD, 0);

    labels_kernel<<<(Wrows + 255) / 256, 256, 0, stream>>>(
        token_ids, window_start, window_end, labels);
    if (fast_decode) {
        cvt_h_kernel<<<1024, 256, 0, stream>>>(h2b, hbf);   // bufC free now
        decode_mfma2_kernel<<<4096, 256, 0, stream>>>(
            hbf, wbf, decode_W, decode_b, labels, pm, ps, lab, dflag);
    } else {
        decode_mfma_kernel<<<dim3(cNVT, Wrows / 128), 256, 0, stream>>>(
            h2b, decode_W, decode_b, labels, pm, ps, lab, dflag);
    }
    lse_reduce_kernel<<<Wrows, 64, 0, stream>>>(pm, ps, lab, labels, logppart);

    finalize_kernel<<<1, 256, 0, stream>>>(velpart, logppart,
        window_start, window_end, d_out, dflag);
}